// Round 3
// baseline (1518.532 us; speedup 1.0000x reference)
//
#include <hip/hip_runtime.h>
#include <hip/hip_bf16.h>
#include <math.h>

#define LOWEST_FREQ (30.0f / 11025.0f)

__device__ __forceinline__ float fast_sin_rev(float rev) {
#if __has_builtin(__builtin_amdgcn_sinf)
    return __builtin_amdgcn_sinf(rev);   // v_sin_f32: sin(2*pi*rev)
#else
    return __sinf(rev * 6.28318530717958647692f);
#endif
}
__device__ __forceinline__ float fast_cos_rev(float rev) {
#if __has_builtin(__builtin_amdgcn_cosf)
    return __builtin_amdgcn_cosf(rev);
#else
    return __cosf(rev * 6.28318530717958647692f);
#endif
}
__device__ __forceinline__ float lrelu(float x) { return x >= 0.f ? x : 0.2f * x; }

// ---------------- conv_in: 1ch -> 112ch 3x3 + concat pos (16ch) ----------------
__global__ __launch_bounds__(256) void conv_in_kernel(
    const float* __restrict__ x, const float* __restrict__ wi,
    const float* __restrict__ bi, const float* __restrict__ pos,
    float* __restrict__ out, int total)
{
    int idx = blockIdx.x * 256 + threadIdx.x;
    if (idx >= total) return;
    int pix = idx & 16383;
    int c   = (idx >> 14) & 127;
    int b   = idx >> 21;
    int y = pix >> 7, xx = pix & 127;
    float v;
    if (c < 112) {
        float acc = bi[c];
        const float* xb = x + (size_t)b * 16384;
        const float* wc = wi + c * 9;
        #pragma unroll
        for (int ky = 0; ky < 3; ++ky) {
            int gy = y + ky - 1;
            if ((unsigned)gy < 128u) {
                #pragma unroll
                for (int kx = 0; kx < 3; ++kx) {
                    int gx = xx + kx - 1;
                    if ((unsigned)gx < 128u)
                        acc = fmaf(wc[ky * 3 + kx], xb[gy * 128 + gx], acc);
                }
            }
        }
        v = acc;
    } else {
        v = pos[(c - 112) * 16384 + pix];
    }
    out[idx] = v;
}

// ---------------- stride-1 3x3 conv, 128->128 ch, column-tiled ----------------
// 128 threads = 2 oc-groups (1 wave each, OCT=8) x 64 px-threads.
// px-thread: X = pt&15 (lane-stride 1 -> conflict-free LDS), 4-tall column.
// Block: 16x16 px tile, 16 out-channels. nOcb=8 -> 1024 blocks at 128x128.
template<int ICCH, bool RELU, bool UP2>
__global__ __launch_bounds__(128) void conv3x3_s1(
    const float* __restrict__ in, const float* __restrict__ w,
    const float* __restrict__ bias, float* __restrict__ out,
    int Hin, int Win)   // logical (post-upsample) input dims == output dims
{
    constexpr int OCT = 8;
    __shared__ float sIn[ICCH][18][18];
    const int tid = threadIdx.x;
    const int pt  = tid & 63;
    const int ocg = __builtin_amdgcn_readfirstlane(tid >> 6);  // 0..1, wave-uniform
    const int X   = pt & 15;          // lane-stride 1 in x
    const int Yc  = pt >> 4;          // 0..3 -> rows 4*Yc .. 4*Yc+3
    const int b   = blockIdx.z >> 3;
    const int ocb = (blockIdx.z & 7) * 16 + ocg * OCT;         // wave-uniform
    const int iy0 = blockIdx.y * 16 - 1;
    const int ix0 = blockIdx.x * 16 - 1;
    const int Hp = UP2 ? (Hin >> 1) : Hin;
    const int Wp = UP2 ? (Win >> 1) : Win;
    const size_t HWp = (size_t)Hp * Wp;

    float acc[OCT][4];
    #pragma unroll
    for (int o = 0; o < OCT; ++o)
        #pragma unroll
        for (int i = 0; i < 4; ++i) acc[o][i] = 0.f;

    for (int ic0 = 0; ic0 < 128; ic0 += ICCH) {
        const float* inb = in + ((size_t)b * 128 + ic0) * HWp;
        constexpr int TOT = ICCH * 18 * 18;
        for (int s = tid; s < TOT; s += 128) {
            int icl = s / 324;
            int rem = s - icl * 324;
            int r = rem / 18;
            int c = rem - r * 18;
            int gy = iy0 + r, gx = ix0 + c;
            float v = 0.f;
            if ((unsigned)gy < (unsigned)Hin && (unsigned)gx < (unsigned)Win) {
                if (UP2) v = inb[icl * HWp + (size_t)(gy >> 1) * Wp + (gx >> 1)];
                else     v = inb[icl * HWp + (size_t)gy * Wp + gx];
            }
            sIn[icl][r][c] = v;
        }
        __syncthreads();
        #pragma unroll 2
        for (int icl = 0; icl < ICCH; ++icl) {
            float vin[6][3];
            #pragma unroll
            for (int r = 0; r < 6; ++r)
                #pragma unroll
                for (int c = 0; c < 3; ++c) vin[r][c] = sIn[icl][4 * Yc + r][X + c];
            const float* wq = w + ((size_t)ocb * 128 + (ic0 + icl)) * 9;
            #pragma unroll
            for (int o = 0; o < OCT; ++o) {
                const float* wo = wq + (size_t)o * 1152;  // 128*9
                float w0 = wo[0], w1 = wo[1], w2 = wo[2];
                float w3 = wo[3], w4 = wo[4], w5 = wo[5];
                float w6 = wo[6], w7 = wo[7], w8 = wo[8];
                #pragma unroll
                for (int i = 0; i < 4; ++i) {
                    float a = acc[o][i];
                    a = fmaf(w0, vin[i + 0][0], a);
                    a = fmaf(w1, vin[i + 0][1], a);
                    a = fmaf(w2, vin[i + 0][2], a);
                    a = fmaf(w3, vin[i + 1][0], a);
                    a = fmaf(w4, vin[i + 1][1], a);
                    a = fmaf(w5, vin[i + 1][2], a);
                    a = fmaf(w6, vin[i + 2][0], a);
                    a = fmaf(w7, vin[i + 2][1], a);
                    a = fmaf(w8, vin[i + 2][2], a);
                    acc[o][i] = a;
                }
            }
        }
        __syncthreads();
    }
    const int ox = blockIdx.x * 16 + X;
    const int oy0 = blockIdx.y * 16 + 4 * Yc;
    #pragma unroll
    for (int o = 0; o < OCT; ++o) {
        float bv = bias[ocb + o];
        #pragma unroll
        for (int i = 0; i < 4; ++i) {
            float r = acc[o][i] + bv;
            if (RELU) r = lrelu(r);
            out[(((size_t)b * 128 + (ocb + o)) * Hin + (oy0 + i)) * Win + ox] = r;
        }
    }
}

// ---------------- stride-2 3x3 conv, 128->128 ch ----------------
// 256 threads = 4 oc-groups x 64 px-threads (8x8 out tile, 1 px each), OCT oc/thread.
template<int ICCH, int OCT, bool RELU>
__global__ __launch_bounds__(256) void conv3x3_s2(
    const float* __restrict__ in, const float* __restrict__ w,
    const float* __restrict__ bias, float* __restrict__ out,
    int Hin, int Win)
{
    __shared__ float sIn[ICCH][17][17];
    const int tid = threadIdx.x;
    const int pt  = tid & 63;
    const int ocg = __builtin_amdgcn_readfirstlane(tid >> 6);
    const int pyt = pt >> 3, pxt = pt & 7;
    constexpr int OC_TILE = OCT * 4;
    const int nOcb = 128 / OC_TILE;
    const int b    = blockIdx.z / nOcb;
    const int ocb  = (blockIdx.z % nOcb) * OC_TILE + ocg * OCT;
    const int Hout = Hin >> 1, Wout = Win >> 1;
    const int iy0  = blockIdx.y * 16 - 1;
    const int ix0  = blockIdx.x * 16 - 1;
    const size_t HW = (size_t)Hin * Win;

    float acc[OCT];
    #pragma unroll
    for (int o = 0; o < OCT; ++o) acc[o] = 0.f;

    for (int ic0 = 0; ic0 < 128; ic0 += ICCH) {
        const float* inb = in + ((size_t)b * 128 + ic0) * HW;
        constexpr int TOT = ICCH * 17 * 17;
        for (int s = tid; s < TOT; s += 256) {
            int icl = s / 289;
            int rem = s - icl * 289;
            int r = rem / 17;
            int c = rem - r * 17;
            int gy = iy0 + r, gx = ix0 + c;
            float v = 0.f;
            if ((unsigned)gy < (unsigned)Hin && (unsigned)gx < (unsigned)Win)
                v = inb[icl * HW + (size_t)gy * Win + gx];
            sIn[icl][r][c] = v;
        }
        __syncthreads();
        #pragma unroll 2
        for (int icl = 0; icl < ICCH; ++icl) {
            float vin[3][3];
            #pragma unroll
            for (int i = 0; i < 3; ++i)
                #pragma unroll
                for (int j = 0; j < 3; ++j) vin[i][j] = sIn[icl][2 * pyt + i][2 * pxt + j];
            const float* wq = w + ((size_t)ocb * 128 + (ic0 + icl)) * 9;
            #pragma unroll
            for (int o = 0; o < OCT; ++o) {
                const float* wo = wq + (size_t)o * 1152;
                float a = acc[o];
                a = fmaf(wo[0], vin[0][0], a);
                a = fmaf(wo[1], vin[0][1], a);
                a = fmaf(wo[2], vin[0][2], a);
                a = fmaf(wo[3], vin[1][0], a);
                a = fmaf(wo[4], vin[1][1], a);
                a = fmaf(wo[5], vin[1][2], a);
                a = fmaf(wo[6], vin[2][0], a);
                a = fmaf(wo[7], vin[2][1], a);
                a = fmaf(wo[8], vin[2][2], a);
                acc[o] = a;
            }
        }
        __syncthreads();
    }
    const int oy = blockIdx.y * 8 + pyt;
    const int ox = blockIdx.x * 8 + pxt;
    #pragma unroll
    for (int o = 0; o < OCT; ++o) {
        float r = acc[o] + bias[ocb + o];
        if (RELU) r = lrelu(r);
        out[(((size_t)b * 128 + (ocb + o)) * Hout + oy) * Wout + ox] = r;
    }
}

// ---------------- per-pixel channel-norm + 1x1 sel conv ----------------
__global__ __launch_bounds__(256) void normsel_kernel(
    const float* __restrict__ h, const float* __restrict__ wsel,
    const float* __restrict__ bsel, float* __restrict__ s_lin, int total)
{
    int idx = blockIdx.x * 256 + threadIdx.x;
    if (idx >= total) return;
    int b = idx >> 14, pix = idx & 16383;
    const float* hb = h + (size_t)b * 128 * 16384 + pix;
    float ss = 0.f, dot = 0.f;
    #pragma unroll 8
    for (int c = 0; c < 128; ++c) {
        float v = hb[(size_t)c * 16384];
        ss = fmaf(v, v, ss);
        dot = fmaf(wsel[c], v, dot);
    }
    s_lin[idx] = dot / (sqrtf(ss) + 1e-8f) + bsel[0];
}

// ---------------- softmax over 16384, write feat_map ----------------
__global__ __launch_bounds__(256) void softmax_kernel(
    const float* __restrict__ s_lin, float* __restrict__ feat)
{
    int b = blockIdx.x;
    const float* src = s_lin + b * 16384;
    __shared__ float red[256];
    int tid = threadIdx.x;
    float m = -INFINITY;
    for (int i = tid; i < 16384; i += 256) m = fmaxf(m, src[i]);
    red[tid] = m;
    __syncthreads();
    for (int off = 128; off > 0; off >>= 1) {
        if (tid < off) red[tid] = fmaxf(red[tid], red[tid + off]);
        __syncthreads();
    }
    m = red[0];
    __syncthreads();
    float s = 0.f;
    for (int i = tid; i < 16384; i += 256) s += expf(src[i] - m);
    red[tid] = s;
    __syncthreads();
    for (int off = 128; off > 0; off >>= 1) {
        if (tid < off) red[tid] += red[tid + off];
        __syncthreads();
    }
    s = red[0];
    float inv = 1.f / s;
    for (int i = tid; i < 16384; i += 256) feat[b * 16384 + i] = expf(src[i] - m) * inv;
}

// ---------------- top-16: per-thread register top-16 + LDS merge ----------------
__global__ __launch_bounds__(256) void topk_kernel(
    const float* __restrict__ s_lin, int* __restrict__ idxOut)
{
    __shared__ float cv[4096];
    __shared__ int   ci[4096];
    __shared__ float sv[256];
    __shared__ int   si[256];
    __shared__ int   sp[256];
    int b = blockIdx.x;
    const float* src = s_lin + b * 16384;
    int tid = threadIdx.x;
    float tv[16]; int ti[16];
    #pragma unroll
    for (int k = 0; k < 16; ++k) { tv[k] = -INFINITY; ti[k] = 0x7fffffff; }
    for (int i = tid; i < 16384; i += 256) {
        float v = src[i];
        if (v > tv[15]) {
            // branch-free ripple insert; ties keep earlier (lower) index
            #pragma unroll
            for (int k = 15; k >= 1; --k) {
                bool sh  = v > tv[k - 1];
                bool ins = (!sh) && (v > tv[k]);
                float nv = sh ? tv[k - 1] : (ins ? v : tv[k]);
                int   ni = sh ? ti[k - 1] : (ins ? i : ti[k]);
                tv[k] = nv; ti[k] = ni;
            }
            bool s0 = v > tv[0];
            tv[0] = s0 ? v : tv[0];
            ti[0] = s0 ? i : ti[0];
        }
    }
    #pragma unroll
    for (int k = 0; k < 16; ++k) { cv[k * 256 + tid] = tv[k]; ci[k * 256 + tid] = ti[k]; }
    __syncthreads();
    for (int k = 0; k < 16; ++k) {
        float bv = -INFINITY; int bi_ = 0x7fffffff; int bp = -1;
        for (int j = tid; j < 4096; j += 256) {
            float v = cv[j]; int id = ci[j];
            if (v > bv || (v == bv && id < bi_)) { bv = v; bi_ = id; bp = j; }
        }
        sv[tid] = bv; si[tid] = bi_; sp[tid] = bp;
        __syncthreads();
        for (int off = 128; off > 0; off >>= 1) {
            if (tid < off) {
                float v2 = sv[tid + off]; int i2 = si[tid + off];
                if (v2 > sv[tid] || (v2 == sv[tid] && i2 < si[tid])) {
                    sv[tid] = v2; si[tid] = i2; sp[tid] = sp[tid + off];
                }
            }
            __syncthreads();
        }
        if (tid == 0) {
            idxOut[b * 16 + k] = si[0];
            cv[sp[0]] = -INFINITY;
        }
        __syncthreads();
    }
}

// ---------------- latents: 1x1 values-conv at 16 selected positions ----------------
__global__ __launch_bounds__(128) void latents_kernel(
    const float* __restrict__ h, const float* __restrict__ wval,
    const float* __restrict__ bval, const int* __restrict__ tki,
    float* __restrict__ outL, float* __restrict__ zbuf)
{
    int bk = blockIdx.x;          // b*16 + k
    int oc = threadIdx.x;         // 0..127
    int b = bk >> 4;
    int pix = tki[bk];
    const float* hb = h + (size_t)b * 128 * 16384 + pix;
    const float* wr = wval + oc * 128;
    float acc = bval[oc];
    #pragma unroll 8
    for (int ic = 0; ic < 128; ++ic) acc = fmaf(wr[ic], hb[(size_t)ic * 16384], acc);
    outL[bk * 128 + oc] = acc;
    zbuf[bk * 128 + oc] = acc;
}

// ---------------- up-projection z(32,128) @ wup(128,512) + bup ----------------
__global__ __launch_bounds__(256) void upproj_kernel(
    const float* __restrict__ zbuf, const float* __restrict__ wup,
    const float* __restrict__ bup, float* __restrict__ u0, int total)
{
    int idx = blockIdx.x * 256 + threadIdx.x;
    if (idx >= total) return;
    int a = idx >> 9, o = idx & 511;
    const float* z = zbuf + a * 128;
    float acc = bup[o];
    #pragma unroll 8
    for (int k = 0; k < 128; ++k) acc = fmaf(z[k], wup[k * 512 + o], acc);
    u0[idx] = acc;
}

// ---------------- conv1d on 2x-repeated input, k=3 pad=1, + lrelu ----------------
template<int LIN>
__global__ __launch_bounds__(256) void conv1dup_kernel(
    const float* __restrict__ in, const float* __restrict__ w,
    const float* __restrict__ bias, float* __restrict__ out, int total)
{
    constexpr int LOUT = 2 * LIN;
    constexpr int SH = (LIN == 4) ? 3 : (LIN == 8) ? 4 : 5;
    int idx = blockIdx.x * 256 + threadIdx.x;
    if (idx >= total) return;
    int t  = idx & (LOUT - 1);
    int oc = (idx >> SH) & 127;
    int a  = idx >> (SH + 7);
    float acc = bias[oc];
    const float* ib = in + (size_t)a * 128 * LIN;
    const float* wr = w + (size_t)oc * 384;
    int im_ = (t - 1) >> 1, i0 = t >> 1, ip = (t + 1) >> 1;
    bool bm = (t - 1) >= 0, bp = (t + 1) < LOUT;
    #pragma unroll 4
    for (int ic = 0; ic < 128; ++ic) {
        const float* ii = ib + ic * LIN;
        const float* ww = wr + ic * 3;
        if (bm) acc = fmaf(ww[0], ii[im_], acc);
        acc = fmaf(ww[1], ii[i0], acc);
        if (bp) acc = fmaf(ww[2], ii[ip], acc);
    }
    out[idx] = lrelu(acc);
}

// ---------------- fused pointwise heads: amp (sq), fr (sigmoid), mags (sq) ----------------
__global__ __launch_bounds__(256) void heads_kernel(
    const float* __restrict__ u,
    const float* __restrict__ wamp, const float* __restrict__ bamp,
    const float* __restrict__ wfr,  const float* __restrict__ bfr,
    const float* __restrict__ wnz,  const float* __restrict__ bnz,
    float* __restrict__ amp, float* __restrict__ fr, float* __restrict__ mags,
    int total)
{
    int idx = blockIdx.x * 256 + threadIdx.x;
    if (idx >= total) return;
    int t  = idx & 31;
    int oc = (idx >> 5) % 385;
    int a  = idx / (32 * 385);
    const float* ib = u + (size_t)a * 4096 + t;
    const float* wr; float bv;
    if (oc < 128)      { wr = wamp + oc * 128;        bv = bamp[oc]; }
    else if (oc < 256) { wr = wfr + (oc - 128) * 128; bv = bfr[oc - 128]; }
    else               { wr = wnz + (oc - 256) * 128; bv = bnz[oc - 256]; }
    float acc = bv;
    #pragma unroll 8
    for (int ic = 0; ic < 128; ++ic) acc = fmaf(wr[ic], ib[ic * 32], acc);
    if (oc < 128) {
        amp[((size_t)a * 128 + oc) * 32 + t] = acc * acc;
    } else if (oc < 256) {
        float s = 1.f / (1.f + expf(-acc));
        fr[((size_t)a * 128 + (oc - 128)) * 32 + t] = LOWEST_FREQ + s * (1.f - LOWEST_FREQ);
    } else {
        mags[((size_t)a * 129 + (oc - 256)) * 32 + t] = acc * acc;
    }
}

// ---------------- per-(a,c) phase-base prefix in double, reduced mod 1 rev ----------------
__global__ __launch_bounds__(256) void prefix_kernel(
    const float* __restrict__ fr, float* __restrict__ pb, int total)
{
    int i = blockIdx.x * 256 + threadIdx.x;   // a*128 + c
    if (i >= total) return;
    const float* f = fr + i * 32;
    float* p = pb + i * 32;
    double s = 0.0;
    for (int j = 0; j < 32; ++j) {
        double t = 128.0 * s;                 // revolutions accumulated by full blocks
        p[j] = (float)(t - floor(t));
        s += (double)f[j];
    }
}

// ---------------- harmonic synth + scatter-add ----------------
__global__ __launch_bounds__(256) void harm_kernel(
    const float* __restrict__ fr, const float* __restrict__ amp,
    const float* __restrict__ pb, const int* __restrict__ tki,
    float* __restrict__ outp, int total)
{
    int idx = blockIdx.x * 256 + threadIdx.x;
    if (idx >= total) return;
    int a = idx >> 13;
    int i = idx & 8191;
    int j = i >> 8;
    float il1 = (float)((i & 255) + 1);
    int base = a * 4096 + j;                  // (a*128 + c)*32 + j
    float acc = 0.f;
    #pragma unroll 4
    for (int c = 0; c < 128; ++c) {
        int o = base + c * 32;                // wave-uniform -> scalar loads
        float f = fr[o];
        float am = amp[o];
        float p = pb[o];
        float rev = fmaf(il1, 0.5f * f, p);   // phase in revolutions
        acc = fmaf(fast_sin_rev(rev), am, acc);
    }
    int b = a >> 4;
    atomicAdd(outp + (size_t)b * 32768 + tki[a] + i, acc);
}

// ---------------- direct rfft of noise (N=256) ----------------
__global__ __launch_bounds__(256) void spec_kernel(
    const float* __restrict__ noise, float* __restrict__ re,
    float* __restrict__ im, int total)
{
    int idx = blockIdx.x * 256 + threadIdx.x;
    if (idx >= total) return;
    int f  = idx % 129;
    int aw = idx / 129;
    const float* np_ = noise + (size_t)aw * 256;
    float sr = 0.f, si = 0.f;
    for (int n = 0; n < 256; ++n) {
        float rev = (float)(f * n) * (1.0f / 256.0f);
        float c = fast_cos_rev(rev);
        float s = fast_sin_rev(rev);
        float v = np_[n];
        sr = fmaf(v, c, sr);
        si = fmaf(v, -s, si);                 // exp(-i theta)
    }
    re[idx] = sr;
    im[idx] = si;
}

// ---------------- irfft(spec * mags) + scatter-add ----------------
__global__ __launch_bounds__(256) void nz_kernel(
    const float* __restrict__ re, const float* __restrict__ im,
    const float* __restrict__ mags, const int* __restrict__ tki,
    float* __restrict__ outp, int total)
{
    int idx = blockIdx.x * 256 + threadIdx.x;
    if (idx >= total) return;
    int t  = idx & 255;
    int w_ = (idx >> 8) & 31;
    int a  = idx >> 13;
    const float* R = re + ((size_t)a * 32 + w_) * 129;
    const float* I = im + ((size_t)a * 32 + w_) * 129;
    const float* M = mags + (size_t)a * 129 * 32 + w_;   // m[f] = M[f*32]
    float acc = R[0] * M[0];
    #pragma unroll 4
    for (int f = 1; f < 128; ++f) {
        float rev = (float)(f * t) * (1.0f / 256.0f);
        float c = fast_cos_rev(rev);
        float s = fast_sin_rev(rev);
        acc = fmaf(2.f * M[f * 32], fmaf(R[f], c, -I[f] * s), acc);
    }
    float sg = (t & 1) ? -1.f : 1.f;
    acc = fmaf(M[128 * 32] * sg, R[128], acc);
    acc *= (1.f / 256.f);
    int b = a >> 4;
    atomicAdd(outp + (size_t)b * 32768 + tki[a] + (w_ << 8) + t, acc);
}

extern "C" void kernel_launch(void* const* d_in, const int* in_sizes, int n_in,
                              void* d_out, int out_size, void* d_ws, size_t ws_size,
                              hipStream_t stream) {
    (void)n_in; (void)ws_size;
    const float* x    = (const float*)d_in[0];
    const float* pos  = (const float*)d_in[1];
    const float* wi   = (const float*)d_in[2];
    const float* bi   = (const float*)d_in[3];
    const float* wp   = (const float*)d_in[4];
    const float* bp   = (const float*)d_in[5];
    const float* ws1  = (const float*)d_in[6];
    const float* bs1  = (const float*)d_in[7];
    const float* ws2  = (const float*)d_in[8];
    const float* bs2  = (const float*)d_in[9];
    const float* ws3  = (const float*)d_in[10];
    const float* bs3  = (const float*)d_in[11];
    const float* ws4  = (const float*)d_in[12];
    const float* bs4  = (const float*)d_in[13];
    const float* wsb  = (const float*)d_in[14];
    const float* bsb  = (const float*)d_in[15];
    const float* wsel = (const float*)d_in[16];
    const float* bsel = (const float*)d_in[17];
    const float* wval = (const float*)d_in[18];
    const float* bval = (const float*)d_in[19];
    const float* wup  = (const float*)d_in[20];
    const float* bup  = (const float*)d_in[21];
    const float* wu1  = (const float*)d_in[22];
    const float* bu1  = (const float*)d_in[23];
    const float* wu2  = (const float*)d_in[24];
    const float* bu2  = (const float*)d_in[25];
    const float* wu3  = (const float*)d_in[26];
    const float* bu3  = (const float*)d_in[27];
    const float* wamp = (const float*)d_in[28];
    const float* bamp = (const float*)d_in[29];
    const float* wfr  = (const float*)d_in[30];
    const float* bfr  = (const float*)d_in[31];
    const float* wnz  = (const float*)d_in[32];
    const float* bnz  = (const float*)d_in[33];
    const float* noise= (const float*)d_in[34];

    const int B = in_sizes[0] / (128 * 128);   // = 2
    float* outp = (float*)d_out;
    float* outL = outp + (size_t)B * 32768;
    float* feat = outL + (size_t)B * 16 * 128;

    float* w0 = (float*)d_ws;
    const size_t BIG = (size_t)B * 128 * 128 * 128;    // per ping-pong buffer
    float* off0 = w0;
    float* off1 = w0 + BIG;
    float* s_lin = off1;                                // reused after conv chain
    float* tscr  = s_lin + (size_t)B * 16384;           // (unused, kept for layout)
    int*   tki   = (int*)(tscr + (size_t)B * 16384);
    float* zbuf  = (float*)(tki + 64);
    float* u0    = zbuf + (size_t)B * 2048;
    float* u1    = u0 + (size_t)B * 65536;
    float* ampb  = u1 + (size_t)B * 65536;
    float* frb   = ampb + (size_t)B * 65536;
    float* pbb   = frb + (size_t)B * 65536;
    float* magsb = pbb + (size_t)B * 65536;
    float* spR   = magsb + (size_t)B * 16 * 129 * 32;
    float* spI   = spR + (size_t)B * 16 * 32 * 129;

    hipMemsetAsync(d_out, 0, (size_t)out_size * sizeof(float), stream);

    // ---- encoder conv chain (up2d fused into ws3/ws4 staging) ----
    {
        int total = B * 128 * 16384;
        conv_in_kernel<<<(total + 255) / 256, 256, 0, stream>>>(x, wi, bi, pos, off0, total);
    }
    conv3x3_s1<16, false, false><<<dim3(8, 8, B * 8), 128, 0, stream>>>(off0, wp, bp, off1, 128, 128);
    conv3x3_s2<16, 8, true ><<<dim3(8, 8, B * 4), 256, 0, stream>>>(off1, ws1, bs1, off0, 128, 128);
    conv3x3_s2<16, 4, true ><<<dim3(4, 4, B * 8), 256, 0, stream>>>(off0, ws2, bs2, off1, 64, 64);
    conv3x3_s1<16, true, true ><<<dim3(4, 4, B * 8), 128, 0, stream>>>(off1, ws3, bs3, off0, 64, 64);
    conv3x3_s1<16, true, true ><<<dim3(8, 8, B * 8), 128, 0, stream>>>(off0, ws4, bs4, off1, 128, 128);
    conv3x3_s1<16, false, false><<<dim3(8, 8, B * 8), 128, 0, stream>>>(off1, wsb, bsb, off0, 128, 128);
    float* h = off0;   // (B,128,128,128)

    // ---- selection ----
    {
        int total = B * 16384;
        normsel_kernel<<<(total + 255) / 256, 256, 0, stream>>>(h, wsel, bsel, s_lin, total);
    }
    softmax_kernel<<<B, 256, 0, stream>>>(s_lin, feat);
    topk_kernel<<<B, 256, 0, stream>>>(s_lin, tki);
    latents_kernel<<<B * 16, 128, 0, stream>>>(h, wval, bval, tki, outL, zbuf);

    // ---- decoder ----
    {
        int total = B * 16 * 512;
        upproj_kernel<<<(total + 255) / 256, 256, 0, stream>>>(zbuf, wup, bup, u0, total);
    }
    {
        int total = B * 16 * 128 * 8;
        conv1dup_kernel<4><<<(total + 255) / 256, 256, 0, stream>>>(u0, wu1, bu1, u1, total);
    }
    {
        int total = B * 16 * 128 * 16;
        conv1dup_kernel<8><<<(total + 255) / 256, 256, 0, stream>>>(u1, wu2, bu2, u0, total);
    }
    {
        int total = B * 16 * 128 * 32;
        conv1dup_kernel<16><<<(total + 255) / 256, 256, 0, stream>>>(u0, wu3, bu3, u1, total);
    }
    {
        int total = B * 16 * 385 * 32;
        heads_kernel<<<(total + 255) / 256, 256, 0, stream>>>(u1, wamp, bamp, wfr, bfr, wnz, bnz,
                                                              ampb, frb, magsb, total);
    }
    {
        int total = B * 16 * 128;
        prefix_kernel<<<(total + 255) / 256, 256, 0, stream>>>(frb, pbb, total);
    }
    {
        int total = B * 16 * 8192;
        harm_kernel<<<(total + 255) / 256, 256, 0, stream>>>(frb, ampb, pbb, tki, outp, total);
    }
    {
        int total = B * 16 * 32 * 129;
        spec_kernel<<<(total + 255) / 256, 256, 0, stream>>>(noise, spR, spI, total);
    }
    {
        int total = B * 16 * 32 * 256;
        nz_kernel<<<(total + 255) / 256, 256, 0, stream>>>(spR, spI, magsb, tki, outp, total);
    }
}

// Round 4
// 1154.616 us; speedup vs baseline: 1.3152x; 1.3152x over previous
//
#include <hip/hip_runtime.h>
#include <hip/hip_bf16.h>
#include <math.h>

#define LOWEST_FREQ (30.0f / 11025.0f)

__device__ __forceinline__ float fast_sin_rev(float rev) {
#if __has_builtin(__builtin_amdgcn_sinf)
    return __builtin_amdgcn_sinf(rev);   // v_sin_f32: sin(2*pi*rev)
#else
    return __sinf(rev * 6.28318530717958647692f);
#endif
}
__device__ __forceinline__ float fast_cos_rev(float rev) {
#if __has_builtin(__builtin_amdgcn_cosf)
    return __builtin_amdgcn_cosf(rev);
#else
    return __cosf(rev * 6.28318530717958647692f);
#endif
}
__device__ __forceinline__ float lrelu(float x) { return x >= 0.f ? x : 0.2f * x; }

// ---------------- conv_in: 1ch -> 112ch 3x3 + concat pos (16ch) ----------------
__global__ __launch_bounds__(256) void conv_in_kernel(
    const float* __restrict__ x, const float* __restrict__ wi,
    const float* __restrict__ bi, const float* __restrict__ pos,
    float* __restrict__ out, int total)
{
    int idx = blockIdx.x * 256 + threadIdx.x;
    if (idx >= total) return;
    int pix = idx & 16383;
    int c   = (idx >> 14) & 127;
    int b   = idx >> 21;
    int y = pix >> 7, xx = pix & 127;
    float v;
    if (c < 112) {
        float acc = bi[c];
        const float* xb = x + (size_t)b * 16384;
        const float* wc = wi + c * 9;
        #pragma unroll
        for (int ky = 0; ky < 3; ++ky) {
            int gy = y + ky - 1;
            if ((unsigned)gy < 128u) {
                #pragma unroll
                for (int kx = 0; kx < 3; ++kx) {
                    int gx = xx + kx - 1;
                    if ((unsigned)gx < 128u)
                        acc = fmaf(wc[ky * 3 + kx], xb[gy * 128 + gx], acc);
                }
            }
        }
        v = acc;
    } else {
        v = pos[(c - 112) * 16384 + pix];
    }
    out[idx] = v;
}

// ---------------- stride-1 3x3 conv, 128->128 ch, column-tiled ----------------
// 256 threads = 4 oc-groups (1 wave each, OCT=4) x 64 px-threads.
// px-thread: X = pt&15 (lane-stride 1 -> 2-way bank aliasing = free), ROWS-tall column.
// Block: 16 x (4*ROWS) px tile, 16 out-channels (nOcb = 8).
template<int ICCH, int ROWS, bool RELU, bool UP2>
__global__ __launch_bounds__(256) void conv3x3_s1(
    const float* __restrict__ in, const float* __restrict__ w,
    const float* __restrict__ bias, float* __restrict__ out,
    int Hin, int Win)   // logical (post-upsample) input dims == output dims
{
    constexpr int OCT = 4;
    constexpr int TH  = 4 * ROWS;
    __shared__ float sIn[ICCH][TH + 2][18];
    const int tid = threadIdx.x;
    const int pt  = tid & 63;
    const int ocg = __builtin_amdgcn_readfirstlane(tid >> 6);  // 0..3, wave-uniform
    const int X   = pt & 15;          // lane-stride 1 in x
    const int Yc  = pt >> 4;          // 0..3 -> rows ROWS*Yc .. ROWS*Yc+ROWS-1
    const int b   = blockIdx.z >> 3;
    const int ocb = (blockIdx.z & 7) * 16 + ocg * OCT;         // wave-uniform
    const int iy0 = blockIdx.y * TH - 1;
    const int ix0 = blockIdx.x * 16 - 1;
    const int Hp = UP2 ? (Hin >> 1) : Hin;
    const int Wp = UP2 ? (Win >> 1) : Win;
    const size_t HWp = (size_t)Hp * Wp;

    float acc[OCT][ROWS];
    #pragma unroll
    for (int o = 0; o < OCT; ++o)
        #pragma unroll
        for (int i = 0; i < ROWS; ++i) acc[o][i] = 0.f;

    for (int ic0 = 0; ic0 < 128; ic0 += ICCH) {
        const float* inb = in + ((size_t)b * 128 + ic0) * HWp;
        constexpr int TOT = ICCH * (TH + 2) * 18;
        for (int s = tid; s < TOT; s += 256) {
            int icl = s / ((TH + 2) * 18);
            int rem = s - icl * ((TH + 2) * 18);
            int r = rem / 18;
            int c = rem - r * 18;
            int gy = iy0 + r, gx = ix0 + c;
            float v = 0.f;
            if ((unsigned)gy < (unsigned)Hin && (unsigned)gx < (unsigned)Win) {
                if (UP2) v = inb[icl * HWp + (size_t)(gy >> 1) * Wp + (gx >> 1)];
                else     v = inb[icl * HWp + (size_t)gy * Wp + gx];
            }
            sIn[icl][r][c] = v;
        }
        __syncthreads();
        #pragma unroll 2
        for (int icl = 0; icl < ICCH; ++icl) {
            float vin[ROWS + 2][3];
            #pragma unroll
            for (int r = 0; r < ROWS + 2; ++r)
                #pragma unroll
                for (int c = 0; c < 3; ++c) vin[r][c] = sIn[icl][ROWS * Yc + r][X + c];
            const float* wq = w + ((size_t)ocb * 128 + (ic0 + icl)) * 9;
            #pragma unroll
            for (int o = 0; o < OCT; ++o) {
                const float* wo = wq + (size_t)o * 1152;  // 128*9
                float w0 = wo[0], w1 = wo[1], w2 = wo[2];
                float w3 = wo[3], w4 = wo[4], w5 = wo[5];
                float w6 = wo[6], w7 = wo[7], w8 = wo[8];
                #pragma unroll
                for (int i = 0; i < ROWS; ++i) {
                    float a = acc[o][i];
                    a = fmaf(w0, vin[i + 0][0], a);
                    a = fmaf(w1, vin[i + 0][1], a);
                    a = fmaf(w2, vin[i + 0][2], a);
                    a = fmaf(w3, vin[i + 1][0], a);
                    a = fmaf(w4, vin[i + 1][1], a);
                    a = fmaf(w5, vin[i + 1][2], a);
                    a = fmaf(w6, vin[i + 2][0], a);
                    a = fmaf(w7, vin[i + 2][1], a);
                    a = fmaf(w8, vin[i + 2][2], a);
                    acc[o][i] = a;
                }
            }
        }
        __syncthreads();
    }
    const int ox = blockIdx.x * 16 + X;
    const int oy0 = blockIdx.y * TH + ROWS * Yc;
    #pragma unroll
    for (int o = 0; o < OCT; ++o) {
        float bv = bias[ocb + o];
        #pragma unroll
        for (int i = 0; i < ROWS; ++i) {
            float r = acc[o][i] + bv;
            if (RELU) r = lrelu(r);
            out[(((size_t)b * 128 + (ocb + o)) * Hin + (oy0 + i)) * Win + ox] = r;
        }
    }
}

// ---------------- stride-2 3x3 conv, 128->128 ch ----------------
// 256 threads = 4 oc-groups x 64 px-threads (8x8 out tile, 1 px each), OCT oc/thread.
template<int ICCH, int OCT, bool RELU>
__global__ __launch_bounds__(256) void conv3x3_s2(
    const float* __restrict__ in, const float* __restrict__ w,
    const float* __restrict__ bias, float* __restrict__ out,
    int Hin, int Win)
{
    __shared__ float sIn[ICCH][17][19];
    const int tid = threadIdx.x;
    const int pt  = tid & 63;
    const int ocg = __builtin_amdgcn_readfirstlane(tid >> 6);
    const int pyt = pt >> 3, pxt = pt & 7;
    constexpr int OC_TILE = OCT * 4;
    const int nOcb = 128 / OC_TILE;
    const int b    = blockIdx.z / nOcb;
    const int ocb  = (blockIdx.z % nOcb) * OC_TILE + ocg * OCT;
    const int Hout = Hin >> 1, Wout = Win >> 1;
    const int iy0  = blockIdx.y * 16 - 1;
    const int ix0  = blockIdx.x * 16 - 1;
    const size_t HW = (size_t)Hin * Win;

    float acc[OCT];
    #pragma unroll
    for (int o = 0; o < OCT; ++o) acc[o] = 0.f;

    for (int ic0 = 0; ic0 < 128; ic0 += ICCH) {
        const float* inb = in + ((size_t)b * 128 + ic0) * HW;
        constexpr int TOT = ICCH * 17 * 17;
        for (int s = tid; s < TOT; s += 256) {
            int icl = s / 289;
            int rem = s - icl * 289;
            int r = rem / 17;
            int c = rem - r * 17;
            int gy = iy0 + r, gx = ix0 + c;
            float v = 0.f;
            if ((unsigned)gy < (unsigned)Hin && (unsigned)gx < (unsigned)Win)
                v = inb[icl * HW + (size_t)gy * Win + gx];
            sIn[icl][r][c] = v;
        }
        __syncthreads();
        #pragma unroll 2
        for (int icl = 0; icl < ICCH; ++icl) {
            float vin[3][3];
            #pragma unroll
            for (int i = 0; i < 3; ++i)
                #pragma unroll
                for (int j = 0; j < 3; ++j) vin[i][j] = sIn[icl][2 * pyt + i][2 * pxt + j];
            const float* wq = w + ((size_t)ocb * 128 + (ic0 + icl)) * 9;
            #pragma unroll
            for (int o = 0; o < OCT; ++o) {
                const float* wo = wq + (size_t)o * 1152;
                float a = acc[o];
                a = fmaf(wo[0], vin[0][0], a);
                a = fmaf(wo[1], vin[0][1], a);
                a = fmaf(wo[2], vin[0][2], a);
                a = fmaf(wo[3], vin[1][0], a);
                a = fmaf(wo[4], vin[1][1], a);
                a = fmaf(wo[5], vin[1][2], a);
                a = fmaf(wo[6], vin[2][0], a);
                a = fmaf(wo[7], vin[2][1], a);
                a = fmaf(wo[8], vin[2][2], a);
                acc[o] = a;
            }
        }
        __syncthreads();
    }
    const int oy = blockIdx.y * 8 + pyt;
    const int ox = blockIdx.x * 8 + pxt;
    #pragma unroll
    for (int o = 0; o < OCT; ++o) {
        float r = acc[o] + bias[ocb + o];
        if (RELU) r = lrelu(r);
        out[(((size_t)b * 128 + (ocb + o)) * Hout + oy) * Wout + ox] = r;
    }
}

// ---------------- per-pixel channel-norm + 1x1 sel conv ----------------
__global__ __launch_bounds__(256) void normsel_kernel(
    const float* __restrict__ h, const float* __restrict__ wsel,
    const float* __restrict__ bsel, float* __restrict__ s_lin, int total)
{
    int idx = blockIdx.x * 256 + threadIdx.x;
    if (idx >= total) return;
    int b = idx >> 14, pix = idx & 16383;
    const float* hb = h + (size_t)b * 128 * 16384 + pix;
    float ss = 0.f, dot = 0.f;
    #pragma unroll 8
    for (int c = 0; c < 128; ++c) {
        float v = hb[(size_t)c * 16384];
        ss = fmaf(v, v, ss);
        dot = fmaf(wsel[c], v, dot);
    }
    s_lin[idx] = dot / (sqrtf(ss) + 1e-8f) + bsel[0];
}

// ---------------- softmax over 16384, write feat_map ----------------
__global__ __launch_bounds__(256) void softmax_kernel(
    const float* __restrict__ s_lin, float* __restrict__ feat)
{
    int b = blockIdx.x;
    const float* src = s_lin + b * 16384;
    __shared__ float red[256];
    int tid = threadIdx.x;
    float m = -INFINITY;
    for (int i = tid; i < 16384; i += 256) m = fmaxf(m, src[i]);
    red[tid] = m;
    __syncthreads();
    for (int off = 128; off > 0; off >>= 1) {
        if (tid < off) red[tid] = fmaxf(red[tid], red[tid + off]);
        __syncthreads();
    }
    m = red[0];
    __syncthreads();
    float s = 0.f;
    for (int i = tid; i < 16384; i += 256) s += expf(src[i] - m);
    red[tid] = s;
    __syncthreads();
    for (int off = 128; off > 0; off >>= 1) {
        if (tid < off) red[tid] += red[tid + off];
        __syncthreads();
    }
    s = red[0];
    float inv = 1.f / s;
    for (int i = tid; i < 16384; i += 256) feat[b * 16384 + i] = expf(src[i] - m) * inv;
}

// ---------------- top-16: per-thread register top-16 + LDS merge ----------------
__global__ __launch_bounds__(256) void topk_kernel(
    const float* __restrict__ s_lin, int* __restrict__ idxOut)
{
    __shared__ float cv[4096];
    __shared__ int   ci[4096];
    __shared__ float sv[256];
    __shared__ int   si[256];
    __shared__ int   sp[256];
    int b = blockIdx.x;
    const float* src = s_lin + b * 16384;
    int tid = threadIdx.x;
    float tv[16]; int ti[16];
    #pragma unroll
    for (int k = 0; k < 16; ++k) { tv[k] = -INFINITY; ti[k] = 0x7fffffff; }
    for (int i = tid; i < 16384; i += 256) {
        float v = src[i];
        if (v > tv[15]) {
            #pragma unroll
            for (int k = 15; k >= 1; --k) {
                bool sh  = v > tv[k - 1];
                bool ins = (!sh) && (v > tv[k]);
                float nv = sh ? tv[k - 1] : (ins ? v : tv[k]);
                int   ni = sh ? ti[k - 1] : (ins ? i : ti[k]);
                tv[k] = nv; ti[k] = ni;
            }
            bool s0 = v > tv[0];
            tv[0] = s0 ? v : tv[0];
            ti[0] = s0 ? i : ti[0];
        }
    }
    #pragma unroll
    for (int k = 0; k < 16; ++k) { cv[k * 256 + tid] = tv[k]; ci[k * 256 + tid] = ti[k]; }
    __syncthreads();
    for (int k = 0; k < 16; ++k) {
        float bv = -INFINITY; int bi_ = 0x7fffffff; int bp = -1;
        for (int j = tid; j < 4096; j += 256) {
            float v = cv[j]; int id = ci[j];
            if (v > bv || (v == bv && id < bi_)) { bv = v; bi_ = id; bp = j; }
        }
        sv[tid] = bv; si[tid] = bi_; sp[tid] = bp;
        __syncthreads();
        for (int off = 128; off > 0; off >>= 1) {
            if (tid < off) {
                float v2 = sv[tid + off]; int i2 = si[tid + off];
                if (v2 > sv[tid] || (v2 == sv[tid] && i2 < si[tid])) {
                    sv[tid] = v2; si[tid] = i2; sp[tid] = sp[tid + off];
                }
            }
            __syncthreads();
        }
        if (tid == 0) {
            idxOut[b * 16 + k] = si[0];
            cv[sp[0]] = -INFINITY;
        }
        __syncthreads();
    }
}

// ---------------- latents: 1x1 values-conv at 16 selected positions ----------------
__global__ __launch_bounds__(128) void latents_kernel(
    const float* __restrict__ h, const float* __restrict__ wval,
    const float* __restrict__ bval, const int* __restrict__ tki,
    float* __restrict__ outL, float* __restrict__ zbuf)
{
    int bk = blockIdx.x;          // b*16 + k
    int oc = threadIdx.x;         // 0..127
    int b = bk >> 4;
    int pix = tki[bk];
    const float* hb = h + (size_t)b * 128 * 16384 + pix;
    const float* wr = wval + oc * 128;
    float acc = bval[oc];
    #pragma unroll 8
    for (int ic = 0; ic < 128; ++ic) acc = fmaf(wr[ic], hb[(size_t)ic * 16384], acc);
    outL[bk * 128 + oc] = acc;
    zbuf[bk * 128 + oc] = acc;
}

// ---------------- up-projection z(32,128) @ wup(128,512) + bup ----------------
__global__ __launch_bounds__(256) void upproj_kernel(
    const float* __restrict__ zbuf, const float* __restrict__ wup,
    const float* __restrict__ bup, float* __restrict__ u0, int total)
{
    int idx = blockIdx.x * 256 + threadIdx.x;
    if (idx >= total) return;
    int a = idx >> 9, o = idx & 511;
    const float* z = zbuf + a * 128;
    float acc = bup[o];
    #pragma unroll 8
    for (int k = 0; k < 128; ++k) acc = fmaf(z[k], wup[k * 512 + o], acc);
    u0[idx] = acc;
}

// ---------------- conv1d on 2x-repeated input, k=3 pad=1, + lrelu ----------------
template<int LIN>
__global__ __launch_bounds__(256) void conv1dup_kernel(
    const float* __restrict__ in, const float* __restrict__ w,
    const float* __restrict__ bias, float* __restrict__ out, int total)
{
    constexpr int LOUT = 2 * LIN;
    constexpr int SH = (LIN == 4) ? 3 : (LIN == 8) ? 4 : 5;
    int idx = blockIdx.x * 256 + threadIdx.x;
    if (idx >= total) return;
    int t  = idx & (LOUT - 1);
    int oc = (idx >> SH) & 127;
    int a  = idx >> (SH + 7);
    float acc = bias[oc];
    const float* ib = in + (size_t)a * 128 * LIN;
    const float* wr = w + (size_t)oc * 384;
    int im_ = (t - 1) >> 1, i0 = t >> 1, ip = (t + 1) >> 1;
    bool bm = (t - 1) >= 0, bp = (t + 1) < LOUT;
    #pragma unroll 4
    for (int ic = 0; ic < 128; ++ic) {
        const float* ii = ib + ic * LIN;
        const float* ww = wr + ic * 3;
        if (bm) acc = fmaf(ww[0], ii[im_], acc);
        acc = fmaf(ww[1], ii[i0], acc);
        if (bp) acc = fmaf(ww[2], ii[ip], acc);
    }
    out[idx] = lrelu(acc);
}

// ---------------- fused pointwise heads: amp (sq), fr (sigmoid), mags (sq) ----------------
__global__ __launch_bounds__(256) void heads_kernel(
    const float* __restrict__ u,
    const float* __restrict__ wamp, const float* __restrict__ bamp,
    const float* __restrict__ wfr,  const float* __restrict__ bfr,
    const float* __restrict__ wnz,  const float* __restrict__ bnz,
    float* __restrict__ amp, float* __restrict__ fr, float* __restrict__ mags,
    int total)
{
    int idx = blockIdx.x * 256 + threadIdx.x;
    if (idx >= total) return;
    int t  = idx & 31;
    int oc = (idx >> 5) % 385;
    int a  = idx / (32 * 385);
    const float* ib = u + (size_t)a * 4096 + t;
    const float* wr; float bv;
    if (oc < 128)      { wr = wamp + oc * 128;        bv = bamp[oc]; }
    else if (oc < 256) { wr = wfr + (oc - 128) * 128; bv = bfr[oc - 128]; }
    else               { wr = wnz + (oc - 256) * 128; bv = bnz[oc - 256]; }
    float acc = bv;
    #pragma unroll 8
    for (int ic = 0; ic < 128; ++ic) acc = fmaf(wr[ic], ib[ic * 32], acc);
    if (oc < 128) {
        amp[((size_t)a * 128 + oc) * 32 + t] = acc * acc;
    } else if (oc < 256) {
        float s = 1.f / (1.f + expf(-acc));
        fr[((size_t)a * 128 + (oc - 128)) * 32 + t] = LOWEST_FREQ + s * (1.f - LOWEST_FREQ);
    } else {
        mags[((size_t)a * 129 + (oc - 256)) * 32 + t] = acc * acc;
    }
}

// ---------------- per-(a,c) phase-base prefix in double, reduced mod 1 rev ----------------
__global__ __launch_bounds__(256) void prefix_kernel(
    const float* __restrict__ fr, float* __restrict__ pb, int total)
{
    int i = blockIdx.x * 256 + threadIdx.x;   // a*128 + c
    if (i >= total) return;
    const float* f = fr + i * 32;
    float* p = pb + i * 32;
    double s = 0.0;
    for (int j = 0; j < 32; ++j) {
        double t = 128.0 * s;                 // revolutions accumulated by full blocks
        p[j] = (float)(t - floor(t));
        s += (double)f[j];
    }
}

// ---------------- harmonic synth + scatter-add ----------------
__global__ __launch_bounds__(256) void harm_kernel(
    const float* __restrict__ fr, const float* __restrict__ amp,
    const float* __restrict__ pb, const int* __restrict__ tki,
    float* __restrict__ outp, int total)
{
    int idx = blockIdx.x * 256 + threadIdx.x;
    if (idx >= total) return;
    int a = idx >> 13;
    int i = idx & 8191;
    int j = i >> 8;
    float il1 = (float)((i & 255) + 1);
    int base = a * 4096 + j;                  // (a*128 + c)*32 + j
    float acc = 0.f;
    #pragma unroll 4
    for (int c = 0; c < 128; ++c) {
        int o = base + c * 32;                // wave-uniform -> scalar loads
        float f = fr[o];
        float am = amp[o];
        float p = pb[o];
        float rev = fmaf(il1, 0.5f * f, p);   // phase in revolutions
        acc = fmaf(fast_sin_rev(rev), am, acc);
    }
    int b = a >> 4;
    atomicAdd(outp + (size_t)b * 32768 + tki[a] + i, acc);
}

// ---------------- direct rfft of noise (N=256) ----------------
__global__ __launch_bounds__(256) void spec_kernel(
    const float* __restrict__ noise, float* __restrict__ re,
    float* __restrict__ im, int total)
{
    int idx = blockIdx.x * 256 + threadIdx.x;
    if (idx >= total) return;
    int f  = idx % 129;
    int aw = idx / 129;
    const float* np_ = noise + (size_t)aw * 256;
    float sr = 0.f, si = 0.f;
    for (int n = 0; n < 256; ++n) {
        float rev = (float)(f * n) * (1.0f / 256.0f);
        float c = fast_cos_rev(rev);
        float s = fast_sin_rev(rev);
        float v = np_[n];
        sr = fmaf(v, c, sr);
        si = fmaf(v, -s, si);                 // exp(-i theta)
    }
    re[idx] = sr;
    im[idx] = si;
}

// ---------------- irfft(spec * mags) + scatter-add ----------------
__global__ __launch_bounds__(256) void nz_kernel(
    const float* __restrict__ re, const float* __restrict__ im,
    const float* __restrict__ mags, const int* __restrict__ tki,
    float* __restrict__ outp, int total)
{
    int idx = blockIdx.x * 256 + threadIdx.x;
    if (idx >= total) return;
    int t  = idx & 255;
    int w_ = (idx >> 8) & 31;
    int a  = idx >> 13;
    const float* R = re + ((size_t)a * 32 + w_) * 129;
    const float* I = im + ((size_t)a * 32 + w_) * 129;
    const float* M = mags + (size_t)a * 129 * 32 + w_;   // m[f] = M[f*32]
    float acc = R[0] * M[0];
    #pragma unroll 4
    for (int f = 1; f < 128; ++f) {
        float rev = (float)(f * t) * (1.0f / 256.0f);
        float c = fast_cos_rev(rev);
        float s = fast_sin_rev(rev);
        acc = fmaf(2.f * M[f * 32], fmaf(R[f], c, -I[f] * s), acc);
    }
    float sg = (t & 1) ? -1.f : 1.f;
    acc = fmaf(M[128 * 32] * sg, R[128], acc);
    acc *= (1.f / 256.f);
    int b = a >> 4;
    atomicAdd(outp + (size_t)b * 32768 + tki[a] + (w_ << 8) + t, acc);
}

extern "C" void kernel_launch(void* const* d_in, const int* in_sizes, int n_in,
                              void* d_out, int out_size, void* d_ws, size_t ws_size,
                              hipStream_t stream) {
    (void)n_in; (void)ws_size;
    const float* x    = (const float*)d_in[0];
    const float* pos  = (const float*)d_in[1];
    const float* wi   = (const float*)d_in[2];
    const float* bi   = (const float*)d_in[3];
    const float* wp   = (const float*)d_in[4];
    const float* bp   = (const float*)d_in[5];
    const float* ws1  = (const float*)d_in[6];
    const float* bs1  = (const float*)d_in[7];
    const float* ws2  = (const float*)d_in[8];
    const float* bs2  = (const float*)d_in[9];
    const float* ws3  = (const float*)d_in[10];
    const float* bs3  = (const float*)d_in[11];
    const float* ws4  = (const float*)d_in[12];
    const float* bs4  = (const float*)d_in[13];
    const float* wsb  = (const float*)d_in[14];
    const float* bsb  = (const float*)d_in[15];
    const float* wsel = (const float*)d_in[16];
    const float* bsel = (const float*)d_in[17];
    const float* wval = (const float*)d_in[18];
    const float* bval = (const float*)d_in[19];
    const float* wup  = (const float*)d_in[20];
    const float* bup  = (const float*)d_in[21];
    const float* wu1  = (const float*)d_in[22];
    const float* bu1  = (const float*)d_in[23];
    const float* wu2  = (const float*)d_in[24];
    const float* bu2  = (const float*)d_in[25];
    const float* wu3  = (const float*)d_in[26];
    const float* bu3  = (const float*)d_in[27];
    const float* wamp = (const float*)d_in[28];
    const float* bamp = (const float*)d_in[29];
    const float* wfr  = (const float*)d_in[30];
    const float* bfr  = (const float*)d_in[31];
    const float* wnz  = (const float*)d_in[32];
    const float* bnz  = (const float*)d_in[33];
    const float* noise= (const float*)d_in[34];

    const int B = in_sizes[0] / (128 * 128);   // = 2
    float* outp = (float*)d_out;
    float* outL = outp + (size_t)B * 32768;
    float* feat = outL + (size_t)B * 16 * 128;

    float* w0 = (float*)d_ws;
    const size_t BIG = (size_t)B * 128 * 128 * 128;    // per ping-pong buffer
    float* off0 = w0;
    float* off1 = w0 + BIG;
    float* s_lin = off1;                                // reused after conv chain
    float* tscr  = s_lin + (size_t)B * 16384;           // (unused, kept for layout)
    int*   tki   = (int*)(tscr + (size_t)B * 16384);
    float* zbuf  = (float*)(tki + 64);
    float* u0    = zbuf + (size_t)B * 2048;
    float* u1    = u0 + (size_t)B * 65536;
    float* ampb  = u1 + (size_t)B * 65536;
    float* frb   = ampb + (size_t)B * 65536;
    float* pbb   = frb + (size_t)B * 65536;
    float* magsb = pbb + (size_t)B * 65536;
    float* spR   = magsb + (size_t)B * 16 * 129 * 32;
    float* spI   = spR + (size_t)B * 16 * 32 * 129;

    hipMemsetAsync(d_out, 0, (size_t)out_size * sizeof(float), stream);

    // ---- encoder conv chain (up2d fused into ws3/ws4 staging) ----
    {
        int total = B * 128 * 16384;
        conv_in_kernel<<<(total + 255) / 256, 256, 0, stream>>>(x, wi, bi, pos, off0, total);
    }
    // wp: 128x128, 1024 blocks x 4 waves
    conv3x3_s1<16, 4, false, false><<<dim3(8, 8, B * 8), 256, 0, stream>>>(off0, wp, bp, off1, 128, 128);
    // ws1: stride2 128->64, 1024 blocks
    conv3x3_s2<8, 4, true ><<<dim3(8, 8, B * 8), 256, 0, stream>>>(off1, ws1, bs1, off0, 128, 128);
    // ws2: stride2 64->32, 256 blocks (small work)
    conv3x3_s2<8, 4, true ><<<dim3(4, 4, B * 8), 256, 0, stream>>>(off0, ws2, bs2, off1, 64, 64);
    // ws3: 64x64 w/ fused upsample from 32x32; 16x8 tile -> 512 blocks
    conv3x3_s1<16, 2, true, true ><<<dim3(4, 8, B * 8), 256, 0, stream>>>(off1, ws3, bs3, off0, 64, 64);
    // ws4: 128x128 w/ fused upsample from 64x64; 1024 blocks
    conv3x3_s1<16, 4, true, true ><<<dim3(8, 8, B * 8), 256, 0, stream>>>(off0, ws4, bs4, off1, 128, 128);
    // wsb: 128x128, 1024 blocks
    conv3x3_s1<16, 4, false, false><<<dim3(8, 8, B * 8), 256, 0, stream>>>(off1, wsb, bsb, off0, 128, 128);
    float* h = off0;   // (B,128,128,128)

    // ---- selection ----
    {
        int total = B * 16384;
        normsel_kernel<<<(total + 255) / 256, 256, 0, stream>>>(h, wsel, bsel, s_lin, total);
    }
    softmax_kernel<<<B, 256, 0, stream>>>(s_lin, feat);
    topk_kernel<<<B, 256, 0, stream>>>(s_lin, tki);
    latents_kernel<<<B * 16, 128, 0, stream>>>(h, wval, bval, tki, outL, zbuf);

    // ---- decoder ----
    {
        int total = B * 16 * 512;
        upproj_kernel<<<(total + 255) / 256, 256, 0, stream>>>(zbuf, wup, bup, u0, total);
    }
    {
        int total = B * 16 * 128 * 8;
        conv1dup_kernel<4><<<(total + 255) / 256, 256, 0, stream>>>(u0, wu1, bu1, u1, total);
    }
    {
        int total = B * 16 * 128 * 16;
        conv1dup_kernel<8><<<(total + 255) / 256, 256, 0, stream>>>(u1, wu2, bu2, u0, total);
    }
    {
        int total = B * 16 * 128 * 32;
        conv1dup_kernel<16><<<(total + 255) / 256, 256, 0, stream>>>(u0, wu3, bu3, u1, total);
    }
    {
        int total = B * 16 * 385 * 32;
        heads_kernel<<<(total + 255) / 256, 256, 0, stream>>>(u1, wamp, bamp, wfr, bfr, wnz, bnz,
                                                              ampb, frb, magsb, total);
    }
    {
        int total = B * 16 * 128;
        prefix_kernel<<<(total + 255) / 256, 256, 0, stream>>>(frb, pbb, total);
    }
    {
        int total = B * 16 * 8192;
        harm_kernel<<<(total + 255) / 256, 256, 0, stream>>>(frb, ampb, pbb, tki, outp, total);
    }
    {
        int total = B * 16 * 32 * 129;
        spec_kernel<<<(total + 255) / 256, 256, 0, stream>>>(noise, spR, spI, total);
    }
    {
        int total = B * 16 * 32 * 256;
        nz_kernel<<<(total + 255) / 256, 256, 0, stream>>>(spR, spI, magsb, tki, outp, total);
    }
}

// Round 5
// 1133.829 us; speedup vs baseline: 1.3393x; 1.0183x over previous
//
#include <hip/hip_runtime.h>
#include <hip/hip_bf16.h>
#include <math.h>

#define LOWEST_FREQ (30.0f / 11025.0f)

__device__ __forceinline__ float fast_sin_rev(float rev) {
#if __has_builtin(__builtin_amdgcn_sinf)
    return __builtin_amdgcn_sinf(rev);   // v_sin_f32: sin(2*pi*rev)
#else
    return __sinf(rev * 6.28318530717958647692f);
#endif
}
__device__ __forceinline__ float fast_cos_rev(float rev) {
#if __has_builtin(__builtin_amdgcn_cosf)
    return __builtin_amdgcn_cosf(rev);
#else
    return __cosf(rev * 6.28318530717958647692f);
#endif
}
__device__ __forceinline__ float lrelu(float x) { return x >= 0.f ? x : 0.2f * x; }

// ---------------- conv_in: 1ch -> 112ch 3x3 + concat pos (16ch) ----------------
__global__ __launch_bounds__(256) void conv_in_kernel(
    const float* __restrict__ x, const float* __restrict__ wi,
    const float* __restrict__ bi, const float* __restrict__ pos,
    float* __restrict__ out, int total)
{
    int idx = blockIdx.x * 256 + threadIdx.x;
    if (idx >= total) return;
    int pix = idx & 16383;
    int c   = (idx >> 14) & 127;
    int b   = idx >> 21;
    int y = pix >> 7, xx = pix & 127;
    float v;
    if (c < 112) {
        float acc = bi[c];
        const float* xb = x + (size_t)b * 16384;
        const float* wc = wi + c * 9;
        #pragma unroll
        for (int ky = 0; ky < 3; ++ky) {
            int gy = y + ky - 1;
            if ((unsigned)gy < 128u) {
                #pragma unroll
                for (int kx = 0; kx < 3; ++kx) {
                    int gx = xx + kx - 1;
                    if ((unsigned)gx < 128u)
                        acc = fmaf(wc[ky * 3 + kx], xb[gy * 128 + gx], acc);
                }
            }
        }
        v = acc;
    } else {
        v = pos[(c - 112) * 16384 + pix];
    }
    out[idx] = v;
}

// ---------------- stride-1 3x3 conv, 128->128 ch, column-tiled ----------------
// 256 threads = 4 oc-groups (1 wave each, OCT=4) x 64 px-threads.
// px-thread: X = pt&15 (lane-stride 1), ROWS-tall column. Block: 16 x (4*ROWS) px,
// 16 out-channels (nOcb=8). PADW padding chosen so 2*... quarter-wave row offsets
// spread banks evenly: need (ROWS*PADW) % 32 == 8 -> ROWS=2: PADW=20; ROWS=1: PADW=24.
template<int ICCH, int ROWS, int PADW, int WV, bool RELU, bool UP2>
__global__ __launch_bounds__(256, WV) void conv3x3_s1(
    const float* __restrict__ in, const float* __restrict__ w,
    const float* __restrict__ bias, float* __restrict__ out,
    int Hin, int Win)   // logical (post-upsample) input dims == output dims
{
    constexpr int OCT = 4;
    constexpr int TH  = 4 * ROWS;
    __shared__ float sIn[ICCH][TH + 2][PADW];
    const int tid = threadIdx.x;
    const int pt  = tid & 63;
    const int ocg = __builtin_amdgcn_readfirstlane(tid >> 6);  // 0..3, wave-uniform
    const int X   = pt & 15;          // lane-stride 1 in x
    const int Yc  = pt >> 4;          // 0..3 -> rows ROWS*Yc .. ROWS*Yc+ROWS-1
    const int b   = blockIdx.z >> 3;
    const int ocb = (blockIdx.z & 7) * 16 + ocg * OCT;         // wave-uniform
    const int iy0 = blockIdx.y * TH - 1;
    const int ix0 = blockIdx.x * 16 - 1;
    const int Hp = UP2 ? (Hin >> 1) : Hin;
    const int Wp = UP2 ? (Win >> 1) : Win;
    const size_t HWp = (size_t)Hp * Wp;

    float acc[OCT][ROWS];
    #pragma unroll
    for (int o = 0; o < OCT; ++o)
        #pragma unroll
        for (int i = 0; i < ROWS; ++i) acc[o][i] = 0.f;

    for (int ic0 = 0; ic0 < 128; ic0 += ICCH) {
        const float* inb = in + ((size_t)b * 128 + ic0) * HWp;
        constexpr int TOT = ICCH * (TH + 2) * 18;
        for (int s = tid; s < TOT; s += 256) {
            int icl = s / ((TH + 2) * 18);
            int rem = s - icl * ((TH + 2) * 18);
            int r = rem / 18;
            int c = rem - r * 18;
            int gy = iy0 + r, gx = ix0 + c;
            float v = 0.f;
            if ((unsigned)gy < (unsigned)Hin && (unsigned)gx < (unsigned)Win) {
                if (UP2) v = inb[icl * HWp + (size_t)(gy >> 1) * Wp + (gx >> 1)];
                else     v = inb[icl * HWp + (size_t)gy * Wp + gx];
            }
            sIn[icl][r][c] = v;
        }
        __syncthreads();
        #pragma unroll 2
        for (int icl = 0; icl < ICCH; ++icl) {
            float vin[ROWS + 2][3];
            #pragma unroll
            for (int r = 0; r < ROWS + 2; ++r)
                #pragma unroll
                for (int c = 0; c < 3; ++c) vin[r][c] = sIn[icl][ROWS * Yc + r][X + c];
            const float* wq = w + ((size_t)ocb * 128 + (ic0 + icl)) * 9;
            #pragma unroll
            for (int o = 0; o < OCT; ++o) {
                const float* wo = wq + (size_t)o * 1152;  // 128*9
                float w0 = wo[0], w1 = wo[1], w2 = wo[2];
                float w3 = wo[3], w4 = wo[4], w5 = wo[5];
                float w6 = wo[6], w7 = wo[7], w8 = wo[8];
                #pragma unroll
                for (int i = 0; i < ROWS; ++i) {
                    float a = acc[o][i];
                    a = fmaf(w0, vin[i + 0][0], a);
                    a = fmaf(w1, vin[i + 0][1], a);
                    a = fmaf(w2, vin[i + 0][2], a);
                    a = fmaf(w3, vin[i + 1][0], a);
                    a = fmaf(w4, vin[i + 1][1], a);
                    a = fmaf(w5, vin[i + 1][2], a);
                    a = fmaf(w6, vin[i + 2][0], a);
                    a = fmaf(w7, vin[i + 2][1], a);
                    a = fmaf(w8, vin[i + 2][2], a);
                    acc[o][i] = a;
                }
            }
        }
        __syncthreads();
    }
    const int ox = blockIdx.x * 16 + X;
    const int oy0 = blockIdx.y * TH + ROWS * Yc;
    #pragma unroll
    for (int o = 0; o < OCT; ++o) {
        float bv = bias[ocb + o];
        #pragma unroll
        for (int i = 0; i < ROWS; ++i) {
            float r = acc[o][i] + bv;
            if (RELU) r = lrelu(r);
            out[(((size_t)b * 128 + (ocb + o)) * Hin + (oy0 + i)) * Win + ox] = r;
        }
    }
}

// ---------------- stride-2 3x3 conv, 128->128 ch, deinterleaved staging ----------------
// 256 threads = 4 oc-groups x 64 px-threads; out tile 16 wide (X=pt&15) x 4 tall.
// Input cols deinterleaved into even/odd LDS arrays so stride-2 taps are stride-1 reads.
// Row width padded to 20: 2*Yc*20 % 32 spreads quarters at {0,8,16,24}.
template<int ICCH, bool RELU>
__global__ __launch_bounds__(256, 4) void conv3x3_s2(
    const float* __restrict__ in, const float* __restrict__ w,
    const float* __restrict__ bias, float* __restrict__ out,
    int Hin, int Win)
{
    constexpr int OCT = 4;
    __shared__ float sE[ICCH][9][20];   // even cols: gx = bx*32 + 2*lx, lx 0..15
    __shared__ float sO[ICCH][9][20];   // odd  cols: gx = bx*32 - 1 + 2*j, j 0..16
    const int tid = threadIdx.x;
    const int pt  = tid & 63;
    const int ocg = __builtin_amdgcn_readfirstlane(tid >> 6);
    const int X   = pt & 15;
    const int Yc  = pt >> 4;            // 0..3
    const int b   = blockIdx.z >> 3;
    const int ocb = (blockIdx.z & 7) * 16 + ocg * OCT;
    const int Hout = Hin >> 1, Wout = Win >> 1;
    const int iy0 = blockIdx.y * 8 - 1;       // 9 input rows
    const int ix0e = blockIdx.x * 32;         // even base
    const int ix0o = blockIdx.x * 32 - 1;     // odd base
    const size_t HW = (size_t)Hin * Win;

    float acc[OCT];
    #pragma unroll
    for (int o = 0; o < OCT; ++o) acc[o] = 0.f;

    for (int ic0 = 0; ic0 < 128; ic0 += ICCH) {
        const float* inb = in + ((size_t)b * 128 + ic0) * HW;
        // even cols
        constexpr int TOTE = ICCH * 9 * 16;
        for (int s = tid; s < TOTE; s += 256) {
            int icl = s / 144;
            int rem = s - icl * 144;
            int r = rem >> 4;
            int lx = rem & 15;
            int gy = iy0 + r, gx = ix0e + 2 * lx;
            float v = 0.f;
            if ((unsigned)gy < (unsigned)Hin && (unsigned)gx < (unsigned)Win)
                v = inb[icl * HW + (size_t)gy * Win + gx];
            sE[icl][r][lx] = v;
        }
        // odd cols
        constexpr int TOTO = ICCH * 9 * 17;
        for (int s = tid; s < TOTO; s += 256) {
            int icl = s / 153;
            int rem = s - icl * 153;
            int r = rem / 17;
            int j = rem - r * 17;
            int gy = iy0 + r, gx = ix0o + 2 * j;
            float v = 0.f;
            if ((unsigned)gy < (unsigned)Hin && (unsigned)gx < (unsigned)Win)
                v = inb[icl * HW + (size_t)gy * Win + gx];
            sO[icl][r][j] = v;
        }
        __syncthreads();
        #pragma unroll 2
        for (int icl = 0; icl < ICCH; ++icl) {
            float vom[3], ve[3], vop[3];
            #pragma unroll
            for (int ky = 0; ky < 3; ++ky) {
                int r = 2 * Yc + ky;
                vom[ky] = sO[icl][r][X];
                ve[ky]  = sE[icl][r][X];
                vop[ky] = sO[icl][r][X + 1];
            }
            const float* wq = w + ((size_t)ocb * 128 + (ic0 + icl)) * 9;
            #pragma unroll
            for (int o = 0; o < OCT; ++o) {
                const float* wo = wq + (size_t)o * 1152;
                float a = acc[o];
                #pragma unroll
                for (int ky = 0; ky < 3; ++ky) {
                    a = fmaf(wo[3 * ky + 0], vom[ky], a);
                    a = fmaf(wo[3 * ky + 1], ve[ky],  a);
                    a = fmaf(wo[3 * ky + 2], vop[ky], a);
                }
                acc[o] = a;
            }
        }
        __syncthreads();
    }
    const int oy = blockIdx.y * 4 + Yc;
    const int ox = blockIdx.x * 16 + X;
    #pragma unroll
    for (int o = 0; o < OCT; ++o) {
        float r = acc[o] + bias[ocb + o];
        if (RELU) r = lrelu(r);
        out[(((size_t)b * 128 + (ocb + o)) * Hout + oy) * Wout + ox] = r;
    }
}

// ---------------- per-pixel channel-norm + 1x1 sel conv ----------------
__global__ __launch_bounds__(256) void normsel_kernel(
    const float* __restrict__ h, const float* __restrict__ wsel,
    const float* __restrict__ bsel, float* __restrict__ s_lin, int total)
{
    int idx = blockIdx.x * 256 + threadIdx.x;
    if (idx >= total) return;
    int b = idx >> 14, pix = idx & 16383;
    const float* hb = h + (size_t)b * 128 * 16384 + pix;
    float ss = 0.f, dot = 0.f;
    #pragma unroll 8
    for (int c = 0; c < 128; ++c) {
        float v = hb[(size_t)c * 16384];
        ss = fmaf(v, v, ss);
        dot = fmaf(wsel[c], v, dot);
    }
    s_lin[idx] = dot / (sqrtf(ss) + 1e-8f) + bsel[0];
}

// ---------------- softmax over 16384, write feat_map ----------------
__global__ __launch_bounds__(256) void softmax_kernel(
    const float* __restrict__ s_lin, float* __restrict__ feat)
{
    int b = blockIdx.x;
    const float* src = s_lin + b * 16384;
    __shared__ float red[256];
    int tid = threadIdx.x;
    float m = -INFINITY;
    for (int i = tid; i < 16384; i += 256) m = fmaxf(m, src[i]);
    red[tid] = m;
    __syncthreads();
    for (int off = 128; off > 0; off >>= 1) {
        if (tid < off) red[tid] = fmaxf(red[tid], red[tid + off]);
        __syncthreads();
    }
    m = red[0];
    __syncthreads();
    float s = 0.f;
    for (int i = tid; i < 16384; i += 256) s += expf(src[i] - m);
    red[tid] = s;
    __syncthreads();
    for (int off = 128; off > 0; off >>= 1) {
        if (tid < off) red[tid] += red[tid + off];
        __syncthreads();
    }
    s = red[0];
    float inv = 1.f / s;
    for (int i = tid; i < 16384; i += 256) feat[b * 16384 + i] = expf(src[i] - m) * inv;
}

// ---------------- top-16: per-thread register top-16 + LDS merge ----------------
__global__ __launch_bounds__(256) void topk_kernel(
    const float* __restrict__ s_lin, int* __restrict__ idxOut)
{
    __shared__ float cv[4096];
    __shared__ int   ci[4096];
    __shared__ float sv[256];
    __shared__ int   si[256];
    __shared__ int   sp[256];
    int b = blockIdx.x;
    const float* src = s_lin + b * 16384;
    int tid = threadIdx.x;
    float tv[16]; int ti[16];
    #pragma unroll
    for (int k = 0; k < 16; ++k) { tv[k] = -INFINITY; ti[k] = 0x7fffffff; }
    for (int i = tid; i < 16384; i += 256) {
        float v = src[i];
        if (v > tv[15]) {
            #pragma unroll
            for (int k = 15; k >= 1; --k) {
                bool sh  = v > tv[k - 1];
                bool ins = (!sh) && (v > tv[k]);
                float nv = sh ? tv[k - 1] : (ins ? v : tv[k]);
                int   ni = sh ? ti[k - 1] : (ins ? i : ti[k]);
                tv[k] = nv; ti[k] = ni;
            }
            bool s0 = v > tv[0];
            tv[0] = s0 ? v : tv[0];
            ti[0] = s0 ? i : ti[0];
        }
    }
    #pragma unroll
    for (int k = 0; k < 16; ++k) { cv[k * 256 + tid] = tv[k]; ci[k * 256 + tid] = ti[k]; }
    __syncthreads();
    for (int k = 0; k < 16; ++k) {
        float bv = -INFINITY; int bi_ = 0x7fffffff; int bp = -1;
        for (int j = tid; j < 4096; j += 256) {
            float v = cv[j]; int id = ci[j];
            if (v > bv || (v == bv && id < bi_)) { bv = v; bi_ = id; bp = j; }
        }
        sv[tid] = bv; si[tid] = bi_; sp[tid] = bp;
        __syncthreads();
        for (int off = 128; off > 0; off >>= 1) {
            if (tid < off) {
                float v2 = sv[tid + off]; int i2 = si[tid + off];
                if (v2 > sv[tid] || (v2 == sv[tid] && i2 < si[tid])) {
                    sv[tid] = v2; si[tid] = i2; sp[tid] = sp[tid + off];
                }
            }
            __syncthreads();
        }
        if (tid == 0) {
            idxOut[b * 16 + k] = si[0];
            cv[sp[0]] = -INFINITY;
        }
        __syncthreads();
    }
}

// ---------------- latents: 1x1 values-conv at 16 selected positions ----------------
__global__ __launch_bounds__(128) void latents_kernel(
    const float* __restrict__ h, const float* __restrict__ wval,
    const float* __restrict__ bval, const int* __restrict__ tki,
    float* __restrict__ outL, float* __restrict__ zbuf)
{
    int bk = blockIdx.x;          // b*16 + k
    int oc = threadIdx.x;         // 0..127
    int b = bk >> 4;
    int pix = tki[bk];
    const float* hb = h + (size_t)b * 128 * 16384 + pix;
    const float* wr = wval + oc * 128;
    float acc = bval[oc];
    #pragma unroll 8
    for (int ic = 0; ic < 128; ++ic) acc = fmaf(wr[ic], hb[(size_t)ic * 16384], acc);
    outL[bk * 128 + oc] = acc;
    zbuf[bk * 128 + oc] = acc;
}

// ---------------- up-projection z(32,128) @ wup(128,512) + bup ----------------
__global__ __launch_bounds__(256) void upproj_kernel(
    const float* __restrict__ zbuf, const float* __restrict__ wup,
    const float* __restrict__ bup, float* __restrict__ u0, int total)
{
    int idx = blockIdx.x * 256 + threadIdx.x;
    if (idx >= total) return;
    int a = idx >> 9, o = idx & 511;
    const float* z = zbuf + a * 128;
    float acc = bup[o];
    #pragma unroll 8
    for (int k = 0; k < 128; ++k) acc = fmaf(z[k], wup[k * 512 + o], acc);
    u0[idx] = acc;
}

// ---------------- conv1d on 2x-repeated input, k=3 pad=1, + lrelu ----------------
template<int LIN>
__global__ __launch_bounds__(256) void conv1dup_kernel(
    const float* __restrict__ in, const float* __restrict__ w,
    const float* __restrict__ bias, float* __restrict__ out, int total)
{
    constexpr int LOUT = 2 * LIN;
    constexpr int SH = (LIN == 4) ? 3 : (LIN == 8) ? 4 : 5;
    int idx = blockIdx.x * 256 + threadIdx.x;
    if (idx >= total) return;
    int t  = idx & (LOUT - 1);
    int oc = (idx >> SH) & 127;
    int a  = idx >> (SH + 7);
    float acc = bias[oc];
    const float* ib = in + (size_t)a * 128 * LIN;
    const float* wr = w + (size_t)oc * 384;
    int im_ = (t - 1) >> 1, i0 = t >> 1, ip = (t + 1) >> 1;
    bool bm = (t - 1) >= 0, bp = (t + 1) < LOUT;
    #pragma unroll 4
    for (int ic = 0; ic < 128; ++ic) {
        const float* ii = ib + ic * LIN;
        const float* ww = wr + ic * 3;
        if (bm) acc = fmaf(ww[0], ii[im_], acc);
        acc = fmaf(ww[1], ii[i0], acc);
        if (bp) acc = fmaf(ww[2], ii[ip], acc);
    }
    out[idx] = lrelu(acc);
}

// ---------------- fused pointwise heads: amp (sq), fr (sigmoid), mags (sq) ----------------
__global__ __launch_bounds__(256) void heads_kernel(
    const float* __restrict__ u,
    const float* __restrict__ wamp, const float* __restrict__ bamp,
    const float* __restrict__ wfr,  const float* __restrict__ bfr,
    const float* __restrict__ wnz,  const float* __restrict__ bnz,
    float* __restrict__ amp, float* __restrict__ fr, float* __restrict__ mags,
    int total)
{
    int idx = blockIdx.x * 256 + threadIdx.x;
    if (idx >= total) return;
    int t  = idx & 31;
    int oc = (idx >> 5) % 385;
    int a  = idx / (32 * 385);
    const float* ib = u + (size_t)a * 4096 + t;
    const float* wr; float bv;
    if (oc < 128)      { wr = wamp + oc * 128;        bv = bamp[oc]; }
    else if (oc < 256) { wr = wfr + (oc - 128) * 128; bv = bfr[oc - 128]; }
    else               { wr = wnz + (oc - 256) * 128; bv = bnz[oc - 256]; }
    float acc = bv;
    #pragma unroll 8
    for (int ic = 0; ic < 128; ++ic) acc = fmaf(wr[ic], ib[ic * 32], acc);
    if (oc < 128) {
        amp[((size_t)a * 128 + oc) * 32 + t] = acc * acc;
    } else if (oc < 256) {
        float s = 1.f / (1.f + expf(-acc));
        fr[((size_t)a * 128 + (oc - 128)) * 32 + t] = LOWEST_FREQ + s * (1.f - LOWEST_FREQ);
    } else {
        mags[((size_t)a * 129 + (oc - 256)) * 32 + t] = acc * acc;
    }
}

// ---------------- per-(a,c) phase-base prefix in double, reduced mod 1 rev ----------------
__global__ __launch_bounds__(256) void prefix_kernel(
    const float* __restrict__ fr, float* __restrict__ pb, int total)
{
    int i = blockIdx.x * 256 + threadIdx.x;   // a*128 + c
    if (i >= total) return;
    const float* f = fr + i * 32;
    float* p = pb + i * 32;
    double s = 0.0;
    for (int j = 0; j < 32; ++j) {
        double t = 128.0 * s;                 // revolutions accumulated by full blocks
        p[j] = (float)(t - floor(t));
        s += (double)f[j];
    }
}

// ---------------- harmonic synth + scatter-add ----------------
__global__ __launch_bounds__(256) void harm_kernel(
    const float* __restrict__ fr, const float* __restrict__ amp,
    const float* __restrict__ pb, const int* __restrict__ tki,
    float* __restrict__ outp, int total)
{
    int idx = blockIdx.x * 256 + threadIdx.x;
    if (idx >= total) return;
    int a = idx >> 13;
    int i = idx & 8191;
    int j = i >> 8;
    float il1 = (float)((i & 255) + 1);
    int base = a * 4096 + j;                  // (a*128 + c)*32 + j
    float acc = 0.f;
    #pragma unroll 4
    for (int c = 0; c < 128; ++c) {
        int o = base + c * 32;                // wave-uniform -> scalar loads
        float f = fr[o];
        float am = amp[o];
        float p = pb[o];
        float rev = fmaf(il1, 0.5f * f, p);   // phase in revolutions
        acc = fmaf(fast_sin_rev(rev), am, acc);
    }
    int b = a >> 4;
    atomicAdd(outp + (size_t)b * 32768 + tki[a] + i, acc);
}

// ---------------- direct rfft of noise (N=256) ----------------
__global__ __launch_bounds__(256) void spec_kernel(
    const float* __restrict__ noise, float* __restrict__ re,
    float* __restrict__ im, int total)
{
    int idx = blockIdx.x * 256 + threadIdx.x;
    if (idx >= total) return;
    int f  = idx % 129;
    int aw = idx / 129;
    const float* np_ = noise + (size_t)aw * 256;
    float sr = 0.f, si = 0.f;
    for (int n = 0; n < 256; ++n) {
        float rev = (float)(f * n) * (1.0f / 256.0f);
        float c = fast_cos_rev(rev);
        float s = fast_sin_rev(rev);
        float v = np_[n];
        sr = fmaf(v, c, sr);
        si = fmaf(v, -s, si);                 // exp(-i theta)
    }
    re[idx] = sr;
    im[idx] = si;
}

// ---------------- irfft(spec * mags) + scatter-add ----------------
__global__ __launch_bounds__(256) void nz_kernel(
    const float* __restrict__ re, const float* __restrict__ im,
    const float* __restrict__ mags, const int* __restrict__ tki,
    float* __restrict__ outp, int total)
{
    int idx = blockIdx.x * 256 + threadIdx.x;
    if (idx >= total) return;
    int t  = idx & 255;
    int w_ = (idx >> 8) & 31;
    int a  = idx >> 13;
    const float* R = re + ((size_t)a * 32 + w_) * 129;
    const float* I = im + ((size_t)a * 32 + w_) * 129;
    const float* M = mags + (size_t)a * 129 * 32 + w_;   // m[f] = M[f*32]
    float acc = R[0] * M[0];
    #pragma unroll 4
    for (int f = 1; f < 128; ++f) {
        float rev = (float)(f * t) * (1.0f / 256.0f);
        float c = fast_cos_rev(rev);
        float s = fast_sin_rev(rev);
        acc = fmaf(2.f * M[f * 32], fmaf(R[f], c, -I[f] * s), acc);
    }
    float sg = (t & 1) ? -1.f : 1.f;
    acc = fmaf(M[128 * 32] * sg, R[128], acc);
    acc *= (1.f / 256.f);
    int b = a >> 4;
    atomicAdd(outp + (size_t)b * 32768 + tki[a] + (w_ << 8) + t, acc);
}

extern "C" void kernel_launch(void* const* d_in, const int* in_sizes, int n_in,
                              void* d_out, int out_size, void* d_ws, size_t ws_size,
                              hipStream_t stream) {
    (void)n_in; (void)ws_size;
    const float* x    = (const float*)d_in[0];
    const float* pos  = (const float*)d_in[1];
    const float* wi   = (const float*)d_in[2];
    const float* bi   = (const float*)d_in[3];
    const float* wp   = (const float*)d_in[4];
    const float* bp   = (const float*)d_in[5];
    const float* ws1  = (const float*)d_in[6];
    const float* bs1  = (const float*)d_in[7];
    const float* ws2  = (const float*)d_in[8];
    const float* bs2  = (const float*)d_in[9];
    const float* ws3  = (const float*)d_in[10];
    const float* bs3  = (const float*)d_in[11];
    const float* ws4  = (const float*)d_in[12];
    const float* bs4  = (const float*)d_in[13];
    const float* wsb  = (const float*)d_in[14];
    const float* bsb  = (const float*)d_in[15];
    const float* wsel = (const float*)d_in[16];
    const float* bsel = (const float*)d_in[17];
    const float* wval = (const float*)d_in[18];
    const float* bval = (const float*)d_in[19];
    const float* wup  = (const float*)d_in[20];
    const float* bup  = (const float*)d_in[21];
    const float* wu1  = (const float*)d_in[22];
    const float* bu1  = (const float*)d_in[23];
    const float* wu2  = (const float*)d_in[24];
    const float* bu2  = (const float*)d_in[25];
    const float* wu3  = (const float*)d_in[26];
    const float* bu3  = (const float*)d_in[27];
    const float* wamp = (const float*)d_in[28];
    const float* bamp = (const float*)d_in[29];
    const float* wfr  = (const float*)d_in[30];
    const float* bfr  = (const float*)d_in[31];
    const float* wnz  = (const float*)d_in[32];
    const float* bnz  = (const float*)d_in[33];
    const float* noise= (const float*)d_in[34];

    const int B = in_sizes[0] / (128 * 128);   // = 2
    float* outp = (float*)d_out;
    float* outL = outp + (size_t)B * 32768;
    float* feat = outL + (size_t)B * 16 * 128;

    float* w0 = (float*)d_ws;
    const size_t BIG = (size_t)B * 128 * 128 * 128;    // per ping-pong buffer
    float* off0 = w0;
    float* off1 = w0 + BIG;
    float* s_lin = off1;                                // reused after conv chain
    float* tscr  = s_lin + (size_t)B * 16384;           // (unused, kept for layout)
    int*   tki   = (int*)(tscr + (size_t)B * 16384);
    float* zbuf  = (float*)(tki + 64);
    float* u0    = zbuf + (size_t)B * 2048;
    float* u1    = u0 + (size_t)B * 65536;
    float* ampb  = u1 + (size_t)B * 65536;
    float* frb   = ampb + (size_t)B * 65536;
    float* pbb   = frb + (size_t)B * 65536;
    float* magsb = pbb + (size_t)B * 65536;
    float* spR   = magsb + (size_t)B * 16 * 129 * 32;
    float* spI   = spR + (size_t)B * 16 * 32 * 129;

    hipMemsetAsync(d_out, 0, (size_t)out_size * sizeof(float), stream);

    // ---- encoder conv chain (up2d fused into ws3/ws4 staging) ----
    {
        int total = B * 128 * 16384;
        conv_in_kernel<<<(total + 255) / 256, 256, 0, stream>>>(x, wi, bi, pos, off0, total);
    }
    // wp: 128x128, 16x8 tiles -> 2048 blocks x 4 waves (8 blocks/CU)
    conv3x3_s1<16, 2, 20, 8, false, false><<<dim3(8, 16, B * 8), 256, 0, stream>>>(off0, wp, bp, off1, 128, 128);
    // ws1: stride2 128->64, 16x4 out tiles -> 1024 blocks
    conv3x3_s2<16, true ><<<dim3(4, 16, B * 8), 256, 0, stream>>>(off1, ws1, bs1, off0, 128, 128);
    // ws2: stride2 64->32, 16x4 out tiles -> 256 blocks
    conv3x3_s2<16, true ><<<dim3(2, 8, B * 8), 256, 0, stream>>>(off0, ws2, bs2, off1, 64, 64);
    // ws3: 64x64 w/ fused upsample from 32x32; 16x4 tiles -> 1024 blocks
    conv3x3_s1<16, 1, 24, 4, true, true ><<<dim3(4, 16, B * 8), 256, 0, stream>>>(off1, ws3, bs3, off0, 64, 64);
    // ws4: 128x128 w/ fused upsample; 2048 blocks
    conv3x3_s1<16, 2, 20, 8, true, true ><<<dim3(8, 16, B * 8), 256, 0, stream>>>(off0, ws4, bs4, off1, 128, 128);
    // wsb: 128x128, 2048 blocks
    conv3x3_s1<16, 2, 20, 8, false, false><<<dim3(8, 16, B * 8), 256, 0, stream>>>(off1, wsb, bsb, off0, 128, 128);
    float* h = off0;   // (B,128,128,128)

    // ---- selection ----
    {
        int total = B * 16384;
        normsel_kernel<<<(total + 255) / 256, 256, 0, stream>>>(h, wsel, bsel, s_lin, total);
    }
    softmax_kernel<<<B, 256, 0, stream>>>(s_lin, feat);
    topk_kernel<<<B, 256, 0, stream>>>(s_lin, tki);
    latents_kernel<<<B * 16, 128, 0, stream>>>(h, wval, bval, tki, outL, zbuf);

    // ---- decoder ----
    {
        int total = B * 16 * 512;
        upproj_kernel<<<(total + 255) / 256, 256, 0, stream>>>(zbuf, wup, bup, u0, total);
    }
    {
        int total = B * 16 * 128 * 8;
        conv1dup_kernel<4><<<(total + 255) / 256, 256, 0, stream>>>(u0, wu1, bu1, u1, total);
    }
    {
        int total = B * 16 * 128 * 16;
        conv1dup_kernel<8><<<(total + 255) / 256, 256, 0, stream>>>(u1, wu2, bu2, u0, total);
    }
    {
        int total = B * 16 * 128 * 32;
        conv1dup_kernel<16><<<(total + 255) / 256, 256, 0, stream>>>(u0, wu3, bu3, u1, total);
    }
    {
        int total = B * 16 * 385 * 32;
        heads_kernel<<<(total + 255) / 256, 256, 0, stream>>>(u1, wamp, bamp, wfr, bfr, wnz, bnz,
                                                              ampb, frb, magsb, total);
    }
    {
        int total = B * 16 * 128;
        prefix_kernel<<<(total + 255) / 256, 256, 0, stream>>>(frb, pbb, total);
    }
    {
        int total = B * 16 * 8192;
        harm_kernel<<<(total + 255) / 256, 256, 0, stream>>>(frb, ampb, pbb, tki, outp, total);
    }
    {
        int total = B * 16 * 32 * 129;
        spec_kernel<<<(total + 255) / 256, 256, 0, stream>>>(noise, spR, spI, total);
    }
    {
        int total = B * 16 * 32 * 256;
        nz_kernel<<<(total + 255) / 256, 256, 0, stream>>>(spR, spI, magsb, tki, outp, total);
    }
}

// Round 8
// 679.056 us; speedup vs baseline: 2.2362x; 1.6697x over previous
//
#include <hip/hip_runtime.h>
#include <hip/hip_bf16.h>
#include <math.h>

#define LOWEST_FREQ (30.0f / 11025.0f)

typedef _Float16 f16x8 __attribute__((ext_vector_type(8)));
typedef _Float16 f16x4 __attribute__((ext_vector_type(4)));
typedef float f32x4 __attribute__((ext_vector_type(4)));

__device__ __forceinline__ float fast_sin_rev(float rev) {
#if __has_builtin(__builtin_amdgcn_sinf)
    return __builtin_amdgcn_sinf(rev);   // v_sin_f32: sin(2*pi*rev)
#else
    return __sinf(rev * 6.28318530717958647692f);
#endif
}
__device__ __forceinline__ float fast_cos_rev(float rev) {
#if __has_builtin(__builtin_amdgcn_cosf)
    return __builtin_amdgcn_cosf(rev);
#else
    return __cosf(rev * 6.28318530717958647692f);
#endif
}
__device__ __forceinline__ float lrelu(float x) { return x >= 0.f ? x : 0.2f * x; }

// ---------------- weight repack: 6 convs, OIHW fp32 -> [tap][oc][ic] fp16 hi/lo ----------------
__global__ __launch_bounds__(256) void repack_kernel(
    const float* __restrict__ w0, const float* __restrict__ w1,
    const float* __restrict__ w2, const float* __restrict__ w3,
    const float* __restrict__ w4, const float* __restrict__ w5,
    _Float16* __restrict__ whi, _Float16* __restrict__ wlo)
{
    int idx = blockIdx.x * 256 + threadIdx.x;
    if (idx >= 6 * 147456) return;
    int j   = idx / 147456;
    int rem = idx - j * 147456;
    int tap = rem >> 14;
    int oc  = (rem >> 7) & 127;
    int ic  = rem & 127;
    const float* src = (j == 0) ? w0 : (j == 1) ? w1 : (j == 2) ? w2 :
                       (j == 3) ? w3 : (j == 4) ? w4 : w5;
    float v = src[(oc * 128 + ic) * 9 + tap];
    _Float16 h = (_Float16)v;
    whi[idx] = h;
    wlo[idx] = (_Float16)(v - (float)h);
}

// ---------------- conv_in: 1ch -> 112ch 3x3 + concat pos; channels-last fp32 out ----------------
__global__ __launch_bounds__(256) void conv_in_kernel(
    const float* __restrict__ x, const float* __restrict__ wi,
    const float* __restrict__ bi, const float* __restrict__ pos,
    float* __restrict__ out, int total)
{
    int idx = blockIdx.x * 256 + threadIdx.x;
    if (idx >= total) return;
    int c   = idx & 127;
    int pix = (idx >> 7) & 16383;
    int b   = idx >> 21;
    int y = pix >> 7, xx = pix & 127;
    float v;
    if (c < 112) {
        float acc = bi[c];
        const float* xb = x + (size_t)b * 16384;
        const float* wc = wi + c * 9;
        #pragma unroll
        for (int ky = 0; ky < 3; ++ky) {
            int gy = y + ky - 1;
            if ((unsigned)gy < 128u) {
                #pragma unroll
                for (int kx = 0; kx < 3; ++kx) {
                    int gx = xx + kx - 1;
                    if ((unsigned)gx < 128u)
                        acc = fmaf(wc[ky * 3 + kx], xb[gy * 128 + gx], acc);
                }
            }
        }
        v = acc;
    } else {
        v = pos[(c - 112) * 16384 + pix];
    }
    out[idx] = v;   // [b][pix][c]
}

// ---------------- split-fp16 MFMA stride-1 3x3 conv (fp32-parity) ----------------
// Block 256 = 4 waves; patch 16w x 8h, 64 oc per block (grid.z = B*2).
// wm=w&1 -> row half; wn=w>>1 -> oc half (2 n-tiles). ic chunked 2x64 (pad 72).
// 3 MFMAs per product: hi*hi + hi*lo + lo*hi.
template<bool UP2, bool RELU>
__global__ __launch_bounds__(256, 2) void mfma_conv_s1(
    const float* __restrict__ in,
    const _Float16* __restrict__ whi, const _Float16* __restrict__ wlo,
    const float* __restrict__ bias, float* __restrict__ out,
    int H, int W)
{
    __shared__ __align__(16) _Float16 sAh[10 * 18 * 72];
    __shared__ __align__(16) _Float16 sAl[10 * 18 * 72];
    const int tid  = threadIdx.x;
    const int w    = tid >> 6, lane = tid & 63;
    const int wm   = w & 1, wn = w >> 1;
    const int lm   = lane & 15, lq = lane >> 4;
    const int b    = blockIdx.z >> 1;
    const int ocb  = (blockIdx.z & 1) * 64;
    const int x0   = blockIdx.x * 16, y0 = blockIdx.y * 8;
    const int iy0  = y0 - 1, ix0 = x0 - 1;
    const int Hp   = UP2 ? (H >> 1) : H;
    const int Wp   = UP2 ? (W >> 1) : W;
    const float* inb = in + (size_t)b * Hp * Wp * 128;

    f32x4 acc[4][2];
    #pragma unroll
    for (int r = 0; r < 4; ++r)
        #pragma unroll
        for (int nt = 0; nt < 2; ++nt) acc[r][nt] = (f32x4){0.f, 0.f, 0.f, 0.f};

    for (int ics = 0; ics < 128; ics += 64) {
        // stage 18x10 px x 64 ic as hi/lo fp16
        for (int e = tid; e < 180 * 16; e += 256) {
            int px  = e >> 4, icq = e & 15;          // icq: group of 4 ic
            int row = px / 18, col = px - row * 18;
            int gy = iy0 + row, gx = ix0 + col;
            f32x4 v = {0.f, 0.f, 0.f, 0.f};
            if ((unsigned)gy < (unsigned)H && (unsigned)gx < (unsigned)W) {
                int sy = UP2 ? (gy >> 1) : gy;
                int sx = UP2 ? (gx >> 1) : gx;
                v = *(const f32x4*)(inb + ((size_t)sy * Wp + sx) * 128 + ics + icq * 4);
            }
            f16x4 hv, lv;
            #pragma unroll
            for (int j = 0; j < 4; ++j) {
                _Float16 h = (_Float16)v[j];
                hv[j] = h;
                lv[j] = (_Float16)(v[j] - (float)h);
            }
            *(f16x4*)&sAh[px * 72 + icq * 4] = hv;
            *(f16x4*)&sAl[px * 72 + icq * 4] = lv;
        }
        __syncthreads();

        for (int ky = 0; ky < 3; ++ky)
        for (int kx = 0; kx < 3; ++kx) {
            const int tap = ky * 3 + kx;
            const _Float16* wth = whi + (size_t)tap * 16384;
            const _Float16* wtl = wlo + (size_t)tap * 16384;
            #pragma unroll
            for (int kc = 0; kc < 2; ++kc) {
                f16x8 bh[2], bl[2];
                #pragma unroll
                for (int nt = 0; nt < 2; ++nt) {
                    int oc = ocb + wn * 32 + nt * 16 + lm;
                    size_t o = (size_t)oc * 128 + ics + kc * 32 + lq * 8;
                    bh[nt] = *(const f16x8*)(wth + o);
                    bl[nt] = *(const f16x8*)(wtl + o);
                }
                #pragma unroll
                for (int r = 0; r < 4; ++r) {
                    int rin = wm * 4 + r + ky;
                    int cin = lm + kx;
                    int o = (rin * 18 + cin) * 72 + kc * 32 + lq * 8;
                    f16x8 ah = *(const f16x8*)(&sAh[o]);
                    f16x8 al = *(const f16x8*)(&sAl[o]);
                    #pragma unroll
                    for (int nt = 0; nt < 2; ++nt) {
                        acc[r][nt] = __builtin_amdgcn_mfma_f32_16x16x32_f16(ah, bh[nt], acc[r][nt], 0, 0, 0);
                        acc[r][nt] = __builtin_amdgcn_mfma_f32_16x16x32_f16(ah, bl[nt], acc[r][nt], 0, 0, 0);
                        acc[r][nt] = __builtin_amdgcn_mfma_f32_16x16x32_f16(al, bh[nt], acc[r][nt], 0, 0, 0);
                    }
                }
            }
        }
        __syncthreads();
    }

    float bv[2];
    #pragma unroll
    for (int nt = 0; nt < 2; ++nt) bv[nt] = bias[ocb + wn * 32 + nt * 16 + lm];
    float* outb = out + (size_t)b * H * W * 128;
    #pragma unroll
    for (int r = 0; r < 4; ++r) {
        int y = y0 + wm * 4 + r;
        #pragma unroll
        for (int nt = 0; nt < 2; ++nt) {
            int oc = ocb + wn * 32 + nt * 16 + lm;
            #pragma unroll
            for (int reg = 0; reg < 4; ++reg) {
                int xo = x0 + lq * 4 + reg;
                float vv = acc[r][nt][reg] + bv[nt];
                if (RELU) vv = lrelu(vv);
                outb[((size_t)y * W + xo) * 128 + oc] = vv;
            }
        }
    }
}

// ---------------- split-fp16 MFMA stride-2 3x3 conv (fp32-parity) ----------------
// Block 256 = 4 waves; out patch 16w x 4h, all 128 oc (wave -> oc quarter).
// Input tile 9 rows x 33 cols, ic-chunked 4x32 (pad 40).
template<bool RELU>
__global__ __launch_bounds__(256, 2) void mfma_conv_s2(
    const float* __restrict__ in,
    const _Float16* __restrict__ whi, const _Float16* __restrict__ wlo,
    const float* __restrict__ bias, float* __restrict__ out,
    int Hin, int Win)
{
    __shared__ __align__(16) _Float16 sAh[9 * 33 * 40];
    __shared__ __align__(16) _Float16 sAl[9 * 33 * 40];
    const int tid  = threadIdx.x;
    const int w    = tid >> 6, lane = tid & 63;
    const int lm   = lane & 15, lq = lane >> 4;
    const int wn   = w;
    const int b    = blockIdx.z;
    const int Wout = Win >> 1;
    const int x0   = blockIdx.x * 16, y0 = blockIdx.y * 4;
    const int iy0  = blockIdx.y * 8 - 1, ix0 = blockIdx.x * 32 - 1;
    const float* inb = in + (size_t)b * Hin * Win * 128;

    f32x4 acc[4][2];
    #pragma unroll
    for (int r = 0; r < 4; ++r)
        #pragma unroll
        for (int nt = 0; nt < 2; ++nt) acc[r][nt] = (f32x4){0.f, 0.f, 0.f, 0.f};

    for (int kc = 0; kc < 4; ++kc) {
        for (int e = tid; e < 297 * 8; e += 256) {
            int px  = e >> 3, icq = e & 7;           // icq: group of 4 ic
            int row = px / 33, col = px - row * 33;
            int gy = iy0 + row, gx = ix0 + col;
            f32x4 v = {0.f, 0.f, 0.f, 0.f};
            if ((unsigned)gy < (unsigned)Hin && (unsigned)gx < (unsigned)Win)
                v = *(const f32x4*)(inb + ((size_t)gy * Win + gx) * 128 + kc * 32 + icq * 4);
            f16x4 hv, lv;
            #pragma unroll
            for (int j = 0; j < 4; ++j) {
                _Float16 h = (_Float16)v[j];
                hv[j] = h;
                lv[j] = (_Float16)(v[j] - (float)h);
            }
            *(f16x4*)&sAh[px * 40 + icq * 4] = hv;
            *(f16x4*)&sAl[px * 40 + icq * 4] = lv;
        }
        __syncthreads();
        for (int ky = 0; ky < 3; ++ky)
        for (int kx = 0; kx < 3; ++kx) {
            const int tap = ky * 3 + kx;
            const _Float16* wth = whi + (size_t)tap * 16384;
            const _Float16* wtl = wlo + (size_t)tap * 16384;
            f16x8 bh[2], bl[2];
            #pragma unroll
            for (int nt = 0; nt < 2; ++nt) {
                int oc = wn * 32 + nt * 16 + lm;
                size_t o = (size_t)oc * 128 + kc * 32 + lq * 8;
                bh[nt] = *(const f16x8*)(wth + o);
                bl[nt] = *(const f16x8*)(wtl + o);
            }
            #pragma unroll
            for (int r = 0; r < 4; ++r) {
                int rin = 2 * r + ky;
                int cin = 2 * lm + kx;
                int o = (rin * 33 + cin) * 40 + lq * 8;
                f16x8 ah = *(const f16x8*)(&sAh[o]);
                f16x8 al = *(const f16x8*)(&sAl[o]);
                #pragma unroll
                for (int nt = 0; nt < 2; ++nt) {
                    acc[r][nt] = __builtin_amdgcn_mfma_f32_16x16x32_f16(ah, bh[nt], acc[r][nt], 0, 0, 0);
                    acc[r][nt] = __builtin_amdgcn_mfma_f32_16x16x32_f16(ah, bl[nt], acc[r][nt], 0, 0, 0);
                    acc[r][nt] = __builtin_amdgcn_mfma_f32_16x16x32_f16(al, bh[nt], acc[r][nt], 0, 0, 0);
                }
            }
        }
        __syncthreads();
    }

    float bv[2];
    #pragma unroll
    for (int nt = 0; nt < 2; ++nt) bv[nt] = bias[wn * 32 + nt * 16 + lm];
    const int Hout = Hin >> 1;
    float* outb = out + (size_t)b * Hout * Wout * 128;
    #pragma unroll
    for (int r = 0; r < 4; ++r) {
        int y = y0 + r;
        #pragma unroll
        for (int nt = 0; nt < 2; ++nt) {
            int oc = wn * 32 + nt * 16 + lm;
            #pragma unroll
            for (int reg = 0; reg < 4; ++reg) {
                int xo = x0 + lq * 4 + reg;
                float vv = acc[r][nt][reg] + bv[nt];
                if (RELU) vv = lrelu(vv);
                outb[((size_t)y * Wout + xo) * 128 + oc] = vv;
            }
        }
    }
}

// ---------------- per-pixel channel-norm + 1x1 sel conv (fp32 h, wave/pixel) ----------------
__global__ __launch_bounds__(256) void normsel_kernel(
    const float* __restrict__ h, const float* __restrict__ wsel,
    const float* __restrict__ bsel, float* __restrict__ s_lin, int totalPix)
{
    int wid = (blockIdx.x * 256 + threadIdx.x) >> 6;
    if (wid >= totalPix) return;
    int lane = threadIdx.x & 63;
    const float* hb = h + (size_t)wid * 128;
    float v1 = hb[lane], v2 = hb[lane + 64];
    float ss  = v1 * v1 + v2 * v2;
    float dot = wsel[lane] * v1 + wsel[lane + 64] * v2;
    #pragma unroll
    for (int off = 32; off > 0; off >>= 1) {
        ss  += __shfl_down(ss, off);
        dot += __shfl_down(dot, off);
    }
    if (lane == 0) s_lin[wid] = dot / (sqrtf(ss) + 1e-8f) + bsel[0];
}

// ---------------- softmax over 16384, write feat_map ----------------
__global__ __launch_bounds__(256) void softmax_kernel(
    const float* __restrict__ s_lin, float* __restrict__ feat)
{
    int b = blockIdx.x;
    const float* src = s_lin + b * 16384;
    __shared__ float red[256];
    int tid = threadIdx.x;
    float m = -INFINITY;
    for (int i = tid; i < 16384; i += 256) m = fmaxf(m, src[i]);
    red[tid] = m;
    __syncthreads();
    for (int off = 128; off > 0; off >>= 1) {
        if (tid < off) red[tid] = fmaxf(red[tid], red[tid + off]);
        __syncthreads();
    }
    m = red[0];
    __syncthreads();
    float s = 0.f;
    for (int i = tid; i < 16384; i += 256) s += expf(src[i] - m);
    red[tid] = s;
    __syncthreads();
    for (int off = 128; off > 0; off >>= 1) {
        if (tid < off) red[tid] += red[tid + off];
        __syncthreads();
    }
    s = red[0];
    float inv = 1.f / s;
    for (int i = tid; i < 16384; i += 256) feat[b * 16384 + i] = expf(src[i] - m) * inv;
}

// ---------------- top-16: per-thread register top-16 + LDS merge ----------------
__global__ __launch_bounds__(256) void topk_kernel(
    const float* __restrict__ s_lin, int* __restrict__ idxOut)
{
    __shared__ float cv[4096];
    __shared__ int   ci[4096];
    __shared__ float sv[256];
    __shared__ int   si[256];
    __shared__ int   sp[256];
    int b = blockIdx.x;
    const float* src = s_lin + b * 16384;
    int tid = threadIdx.x;
    float tv[16]; int ti[16];
    #pragma unroll
    for (int k = 0; k < 16; ++k) { tv[k] = -INFINITY; ti[k] = 0x7fffffff; }
    for (int i = tid; i < 16384; i += 256) {
        float v = src[i];
        if (v > tv[15]) {
            #pragma unroll
            for (int k = 15; k >= 1; --k) {
                bool sh  = v > tv[k - 1];
                bool ins = (!sh) && (v > tv[k]);
                float nv = sh ? tv[k - 1] : (ins ? v : tv[k]);
                int   ni = sh ? ti[k - 1] : (ins ? i : ti[k]);
                tv[k] = nv; ti[k] = ni;
            }
            bool s0 = v > tv[0];
            tv[0] = s0 ? v : tv[0];
            ti[0] = s0 ? i : ti[0];
        }
    }
    #pragma unroll
    for (int k = 0; k < 16; ++k) { cv[k * 256 + tid] = tv[k]; ci[k * 256 + tid] = ti[k]; }
    __syncthreads();
    for (int k = 0; k < 16; ++k) {
        float bv = -INFINITY; int bi_ = 0x7fffffff; int bp = -1;
        for (int j = tid; j < 4096; j += 256) {
            float v = cv[j]; int id = ci[j];
            if (v > bv || (v == bv && id < bi_)) { bv = v; bi_ = id; bp = j; }
        }
        sv[tid] = bv; si[tid] = bi_; sp[tid] = bp;
        __syncthreads();
        for (int off = 128; off > 0; off >>= 1) {
            if (tid < off) {
                float v2 = sv[tid + off]; int i2 = si[tid + off];
                if (v2 > sv[tid] || (v2 == sv[tid] && i2 < si[tid])) {
                    sv[tid] = v2; si[tid] = i2; sp[tid] = sp[tid + off];
                }
            }
            __syncthreads();
        }
        if (tid == 0) {
            idxOut[b * 16 + k] = si[0] & 16383;   // never emit an OOB index
            cv[sp[0]] = -INFINITY;
        }
        __syncthreads();
    }
}

// ---------------- latents: 1x1 values-conv at 16 selected positions (fp32 h) ----------------
__global__ __launch_bounds__(128) void latents_kernel(
    const float* __restrict__ h, const float* __restrict__ wval,
    const float* __restrict__ bval, const int* __restrict__ tki,
    float* __restrict__ outL, float* __restrict__ zbuf)
{
    int bk = blockIdx.x;          // b*16 + k
    int oc = threadIdx.x;         // 0..127
    int b = bk >> 4;
    int pix = tki[bk] & 16383;
    const float* hb = h + ((size_t)b * 16384 + pix) * 128;
    const float* wr = wval + oc * 128;
    float acc = bval[oc];
    #pragma unroll 8
    for (int ic = 0; ic < 128; ++ic) acc = fmaf(wr[ic], hb[ic], acc);
    outL[bk * 128 + oc] = acc;
    zbuf[bk * 128 + oc] = acc;
}

// ---------------- up-projection z(32,128) @ wup(128,512) + bup ----------------
__global__ __launch_bounds__(256) void upproj_kernel(
    const float* __restrict__ zbuf, const float* __restrict__ wup,
    const float* __restrict__ bup, float* __restrict__ u0, int total)
{
    int idx = blockIdx.x * 256 + threadIdx.x;
    if (idx >= total) return;
    int a = idx >> 9, o = idx & 511;
    const float* z = zbuf + a * 128;
    float acc = bup[o];
    #pragma unroll 8
    for (int k = 0; k < 128; ++k) acc = fmaf(z[k], wup[k * 512 + o], acc);
    u0[idx] = acc;
}

// ---------------- conv1d on 2x-repeated input, k=3 pad=1, + lrelu ----------------
template<int LIN>
__global__ __launch_bounds__(256) void conv1dup_kernel(
    const float* __restrict__ in, const float* __restrict__ w,
    const float* __restrict__ bias, float* __restrict__ out, int total)
{
    constexpr int LOUT = 2 * LIN;
    constexpr int SH = (LIN == 4) ? 3 : (LIN == 8) ? 4 : 5;
    int idx = blockIdx.x * 256 + threadIdx.x;
    if (idx >= total) return;
    int t  = idx & (LOUT - 1);
    int oc = (idx >> SH) & 127;
    int a  = idx >> (SH + 7);
    float acc = bias[oc];
    const float* ib = in + (size_t)a * 128 * LIN;
    const float* wr = w + (size_t)oc * 384;
    int im_ = (t - 1) >> 1, i0 = t >> 1, ip = (t + 1) >> 1;
    bool bm = (t - 1) >= 0, bp = (t + 1) < LOUT;
    #pragma unroll 4
    for (int ic = 0; ic < 128; ++ic) {
        const float* ii = ib + ic * LIN;
        const float* ww = wr + ic * 3;
        if (bm) acc = fmaf(ww[0], ii[im_], acc);
        acc = fmaf(ww[1], ii[i0], acc);
        if (bp) acc = fmaf(ww[2], ii[ip], acc);
    }
    out[idx] = lrelu(acc);
}

// ---------------- fused pointwise heads: amp (sq), fr (sigmoid), mags (sq) ----------------
__global__ __launch_bounds__(256) void heads_kernel(
    const float* __restrict__ u,
    const float* __restrict__ wamp, const float* __restrict__ bamp,
    const float* __restrict__ wfr,  const float* __restrict__ bfr,
    const float* __restrict__ wnz,  const float* __restrict__ bnz,
    float* __restrict__ amp, float* __restrict__ fr, float* __restrict__ mags,
    int total)
{
    int idx = blockIdx.x * 256 + threadIdx.x;
    if (idx >= total) return;
    int t  = idx & 31;
    int oc = (idx >> 5) % 385;
    int a  = idx / (32 * 385);
    const float* ib = u + (size_t)a * 4096 + t;
    const float* wr; float bv;
    if (oc < 128)      { wr = wamp + oc * 128;        bv = bamp[oc]; }
    else if (oc < 256) { wr = wfr + (oc - 128) * 128; bv = bfr[oc - 128]; }
    else               { wr = wnz + (oc - 256) * 128; bv = bnz[oc - 256]; }
    float acc = bv;
    #pragma unroll 8
    for (int ic = 0; ic < 128; ++ic) acc = fmaf(wr[ic], ib[ic * 32], acc);
    if (oc < 128) {
        amp[((size_t)a * 128 + oc) * 32 + t] = acc * acc;
    } else if (oc < 256) {
        float s = 1.f / (1.f + expf(-acc));
        fr[((size_t)a * 128 + (oc - 128)) * 32 + t] = LOWEST_FREQ + s * (1.f - LOWEST_FREQ);
    } else {
        mags[((size_t)a * 129 + (oc - 256)) * 32 + t] = acc * acc;
    }
}

// ---------------- per-(a,c) phase-base prefix in double, reduced mod 1 rev ----------------
__global__ __launch_bounds__(256) void prefix_kernel(
    const float* __restrict__ fr, float* __restrict__ pb, int total)
{
    int i = blockIdx.x * 256 + threadIdx.x;   // a*128 + c
    if (i >= total) return;
    const float* f = fr + i * 32;
    float* p = pb + i * 32;
    double s = 0.0;
    for (int j = 0; j < 32; ++j) {
        double t = 128.0 * s;                 // revolutions accumulated by full blocks
        p[j] = (float)(t - floor(t));
        s += (double)f[j];
    }
}

// ---------------- harmonic synth + scatter-add ----------------
__global__ __launch_bounds__(256) void harm_kernel(
    const float* __restrict__ fr, const float* __restrict__ amp,
    const float* __restrict__ pb, const int* __restrict__ tki,
    float* __restrict__ outp, int total)
{
    int idx = blockIdx.x * 256 + threadIdx.x;
    if (idx >= total) return;
    int a = idx >> 13;
    int i = idx & 8191;
    int j = i >> 8;
    float il1 = (float)((i & 255) + 1);
    int base = a * 4096 + j;                  // (a*128 + c)*32 + j
    float acc = 0.f;
    #pragma unroll 4
    for (int c = 0; c < 128; ++c) {
        int o = base + c * 32;                // wave-uniform -> scalar loads
        float f = fr[o];
        float am = amp[o];
        float p = pb[o];
        float rev = fmaf(il1, 0.5f * f, p);   // phase in revolutions
        acc = fmaf(fast_sin_rev(rev), am, acc);
    }
    int b = a >> 4;
    atomicAdd(outp + (size_t)b * 32768 + (tki[a] & 16383) + i, acc);
}

// ---------------- direct rfft of noise (N=256) ----------------
__global__ __launch_bounds__(256) void spec_kernel(
    const float* __restrict__ noise, float* __restrict__ re,
    float* __restrict__ im, int total)
{
    int idx = blockIdx.x * 256 + threadIdx.x;
    if (idx >= total) return;
    int f  = idx % 129;
    int aw = idx / 129;
    const float* np_ = noise + (size_t)aw * 256;
    float sr = 0.f, si = 0.f;
    for (int n = 0; n < 256; ++n) {
        float rev = (float)(f * n) * (1.0f / 256.0f);
        float c = fast_cos_rev(rev);
        float s = fast_sin_rev(rev);
        float v = np_[n];
        sr = fmaf(v, c, sr);
        si = fmaf(v, -s, si);                 // exp(-i theta)
    }
    re[idx] = sr;
    im[idx] = si;
}

// ---------------- irfft(spec * mags) + scatter-add ----------------
__global__ __launch_bounds__(256) void nz_kernel(
    const float* __restrict__ re, const float* __restrict__ im,
    const float* __restrict__ mags, const int* __restrict__ tki,
    float* __restrict__ outp, int total)
{
    int idx = blockIdx.x * 256 + threadIdx.x;
    if (idx >= total) return;
    int t  = idx & 255;
    int w_ = (idx >> 8) & 31;
    int a  = idx >> 13;
    const float* R = re + ((size_t)a * 32 + w_) * 129;
    const float* I = im + ((size_t)a * 32 + w_) * 129;
    const float* M = mags + (size_t)a * 129 * 32 + w_;   // m[f] = M[f*32]
    float acc = R[0] * M[0];
    #pragma unroll 4
    for (int f = 1; f < 128; ++f) {
        float rev = (float)(f * t) * (1.0f / 256.0f);
        float c = fast_cos_rev(rev);
        float s = fast_sin_rev(rev);
        acc = fmaf(2.f * M[f * 32], fmaf(R[f], c, -I[f] * s), acc);
    }
    float sg = (t & 1) ? -1.f : 1.f;
    acc = fmaf(M[128 * 32] * sg, R[128], acc);
    acc *= (1.f / 256.f);
    int b = a >> 4;
    atomicAdd(outp + (size_t)b * 32768 + (tki[a] & 16383) + (w_ << 8) + t, acc);
}

extern "C" void kernel_launch(void* const* d_in, const int* in_sizes, int n_in,
                              void* d_out, int out_size, void* d_ws, size_t ws_size,
                              hipStream_t stream) {
    (void)n_in; (void)ws_size;
    const float* x    = (const float*)d_in[0];
    const float* pos  = (const float*)d_in[1];
    const float* wi   = (const float*)d_in[2];
    const float* bi   = (const float*)d_in[3];
    const float* wp   = (const float*)d_in[4];
    const float* bp   = (const float*)d_in[5];
    const float* ws1  = (const float*)d_in[6];
    const float* bs1  = (const float*)d_in[7];
    const float* ws2  = (const float*)d_in[8];
    const float* bs2  = (const float*)d_in[9];
    const float* ws3  = (const float*)d_in[10];
    const float* bs3  = (const float*)d_in[11];
    const float* ws4  = (const float*)d_in[12];
    const float* bs4  = (const float*)d_in[13];
    const float* wsb  = (const float*)d_in[14];
    const float* bsb  = (const float*)d_in[15];
    const float* wsel = (const float*)d_in[16];
    const float* bsel = (const float*)d_in[17];
    const float* wval = (const float*)d_in[18];
    const float* bval = (const float*)d_in[19];
    const float* wup  = (const float*)d_in[20];
    const float* bup  = (const float*)d_in[21];
    const float* wu1  = (const float*)d_in[22];
    const float* bu1  = (const float*)d_in[23];
    const float* wu2  = (const float*)d_in[24];
    const float* bu2  = (const float*)d_in[25];
    const float* wu3  = (const float*)d_in[26];
    const float* bu3  = (const float*)d_in[27];
    const float* wamp = (const float*)d_in[28];
    const float* bamp = (const float*)d_in[29];
    const float* wfr  = (const float*)d_in[30];
    const float* bfr  = (const float*)d_in[31];
    const float* wnz  = (const float*)d_in[32];
    const float* bnz  = (const float*)d_in[33];
    const float* noise= (const float*)d_in[34];

    const int B = in_sizes[0] / (128 * 128);   // = 2
    float* outp = (float*)d_out;
    float* outL = outp + (size_t)B * 32768;
    float* feat = outL + (size_t)B * 16 * 128;

    // ---- workspace layout: all regions DISJOINT ----
    // [hb0 fp32][hb1 fp32][whi][wlo][fp32 smalls...]
    const size_t BIGF = (size_t)B * 16384 * 128;       // fp32 feature buffer elements
    float* hb0 = (float*)d_ws;
    float* hb1 = hb0 + BIGF;
    _Float16* whi = (_Float16*)(hb1 + BIGF);
    _Float16* wlo = whi + 6 * 147456;
    float* s_lin = (float*)(wlo + 6 * 147456);
    float* tscr  = s_lin + (size_t)B * 16384;          // spare
    int*   tki   = (int*)(tscr + (size_t)B * 16384);
    float* zbuf  = (float*)(tki + 64);
    float* u0    = zbuf + (size_t)B * 2048;
    float* u1    = u0 + (size_t)B * 65536;
    float* ampb  = u1 + (size_t)B * 65536;
    float* frb   = ampb + (size_t)B * 65536;
    float* pbb   = frb + (size_t)B * 65536;
    float* magsb = pbb + (size_t)B * 65536;
    float* spR   = magsb + (size_t)B * 16 * 129 * 32;
    float* spI   = spR + (size_t)B * 16 * 32 * 129;

    hipMemsetAsync(d_out, 0, (size_t)out_size * sizeof(float), stream);

    repack_kernel<<<(6 * 147456 + 255) / 256, 256, 0, stream>>>(wp, ws1, ws2, ws3, ws4, wsb, whi, wlo);

    // ---- encoder conv chain (channels-last fp32; up2d fused in staging) ----
    {
        int total = B * 128 * 16384;
        conv_in_kernel<<<(total + 255) / 256, 256, 0, stream>>>(x, wi, bi, pos, hb0, total);
    }
    mfma_conv_s1<false, false><<<dim3(8, 16, B * 2), 256, 0, stream>>>(hb0, whi + 0 * 147456, wlo + 0 * 147456, bp,  hb1, 128, 128);
    mfma_conv_s2<true        ><<<dim3(4, 16, B),     256, 0, stream>>>(hb1, whi + 1 * 147456, wlo + 1 * 147456, bs1, hb0, 128, 128);
    mfma_conv_s2<true        ><<<dim3(2, 8,  B),     256, 0, stream>>>(hb0, whi + 2 * 147456, wlo + 2 * 147456, bs2, hb1, 64, 64);
    mfma_conv_s1<true, true  ><<<dim3(4, 8,  B * 2), 256, 0, stream>>>(hb1, whi + 3 * 147456, wlo + 3 * 147456, bs3, hb0, 64, 64);
    mfma_conv_s1<true, true  ><<<dim3(8, 16, B * 2), 256, 0, stream>>>(hb0, whi + 4 * 147456, wlo + 4 * 147456, bs4, hb1, 128, 128);
    mfma_conv_s1<false, false><<<dim3(8, 16, B * 2), 256, 0, stream>>>(hb1, whi + 5 * 147456, wlo + 5 * 147456, bsb, hb0, 128, 128);
    float* h = hb0;   // (B,16384,128) channels-last fp32

    // ---- selection ----
    {
        int totalPix = B * 16384;
        normsel_kernel<<<(totalPix * 64 + 255) / 256, 256, 0, stream>>>(h, wsel, bsel, s_lin, totalPix);
    }
    softmax_kernel<<<B, 256, 0, stream>>>(s_lin, feat);
    topk_kernel<<<B, 256, 0, stream>>>(s_lin, tki);
    latents_kernel<<<B * 16, 128, 0, stream>>>(h, wval, bval, tki, outL, zbuf);

    // ---- decoder ----
    {
        int total = B * 16 * 512;
        upproj_kernel<<<(total + 255) / 256, 256, 0, stream>>>(zbuf, wup, bup, u0, total);
    }
    {
        int total = B * 16 * 128 * 8;
        conv1dup_kernel<4><<<(total + 255) / 256, 256, 0, stream>>>(u0, wu1, bu1, u1, total);
    }
    {
        int total = B * 16 * 128 * 16;
        conv1dup_kernel<8><<<(total + 255) / 256, 256, 0, stream>>>(u1, wu2, bu2, u0, total);
    }
    {
        int total = B * 16 * 128 * 32;
        conv1dup_kernel<16><<<(total + 255) / 256, 256, 0, stream>>>(u0, wu3, bu3, u1, total);
    }
    {
        int total = B * 16 * 385 * 32;
        heads_kernel<<<(total + 255) / 256, 256, 0, stream>>>(u1, wamp, bamp, wfr, bfr, wnz, bnz,
                                                              ampb, frb, magsb, total);
    }
    {
        int total = B * 16 * 128;
        prefix_kernel<<<(total + 255) / 256, 256, 0, stream>>>(frb, pbb, total);
    }
    {
        int total = B * 16 * 8192;
        harm_kernel<<<(total + 255) / 256, 256, 0, stream>>>(frb, ampb, pbb, tki, outp, total);
    }
    {
        int total = B * 16 * 32 * 129;
        spec_kernel<<<(total + 255) / 256, 256, 0, stream>>>(noise, spR, spI, total);
    }
    {
        int total = B * 16 * 32 * 256;
        nz_kernel<<<(total + 255) / 256, 256, 0, stream>>>(spR, spI, magsb, tki, outp, total);
    }
}

// Round 12
// 677.070 us; speedup vs baseline: 2.2428x; 1.0029x over previous
//
#include <hip/hip_runtime.h>
#include <hip/hip_bf16.h>
#include <math.h>

#define LOWEST_FREQ (30.0f / 11025.0f)

typedef _Float16 f16x8 __attribute__((ext_vector_type(8)));
typedef _Float16 f16x4 __attribute__((ext_vector_type(4)));
typedef float f32x4 __attribute__((ext_vector_type(4)));

__device__ __forceinline__ float fast_sin_rev(float rev) {
#if __has_builtin(__builtin_amdgcn_sinf)
    return __builtin_amdgcn_sinf(rev);   // v_sin_f32: sin(2*pi*rev)
#else
    return __sinf(rev * 6.28318530717958647692f);
#endif
}
__device__ __forceinline__ float fast_cos_rev(float rev) {
#if __has_builtin(__builtin_amdgcn_cosf)
    return __builtin_amdgcn_cosf(rev);
#else
    return __cosf(rev * 6.28318530717958647692f);
#endif
}
__device__ __forceinline__ float lrelu(float x) { return x >= 0.f ? x : 0.2f * x; }

// ---------------- weight repack: 6 convs, OIHW fp32 -> [tap][oc][ic] fp16 hi/lo ----------------
__global__ __launch_bounds__(256) void repack_kernel(
    const float* __restrict__ w0, const float* __restrict__ w1,
    const float* __restrict__ w2, const float* __restrict__ w3,
    const float* __restrict__ w4, const float* __restrict__ w5,
    _Float16* __restrict__ whi, _Float16* __restrict__ wlo)
{
    int idx = blockIdx.x * 256 + threadIdx.x;
    if (idx >= 6 * 147456) return;
    int j   = idx / 147456;
    int rem = idx - j * 147456;
    int tap = rem >> 14;
    int oc  = (rem >> 7) & 127;
    int ic  = rem & 127;
    const float* src = (j == 0) ? w0 : (j == 1) ? w1 : (j == 2) ? w2 :
                       (j == 3) ? w3 : (j == 4) ? w4 : w5;
    float v = src[(oc * 128 + ic) * 9 + tap];
    _Float16 h = (_Float16)v;
    whi[idx] = h;
    wlo[idx] = (_Float16)(v - (float)h);
}

// ---------------- conv_in: 1ch -> 112ch 3x3 + concat pos; channels-last fp32 out ----------------
__global__ __launch_bounds__(256) void conv_in_kernel(
    const float* __restrict__ x, const float* __restrict__ wi,
    const float* __restrict__ bi, const float* __restrict__ pos,
    float* __restrict__ out, int total)
{
    int idx = blockIdx.x * 256 + threadIdx.x;
    if (idx >= total) return;
    int c   = idx & 127;
    int pix = (idx >> 7) & 16383;
    int b   = idx >> 21;
    int y = pix >> 7, xx = pix & 127;
    float v;
    if (c < 112) {
        float acc = bi[c];
        const float* xb = x + (size_t)b * 16384;
        const float* wc = wi + c * 9;
        #pragma unroll
        for (int ky = 0; ky < 3; ++ky) {
            int gy = y + ky - 1;
            if ((unsigned)gy < 128u) {
                #pragma unroll
                for (int kx = 0; kx < 3; ++kx) {
                    int gx = xx + kx - 1;
                    if ((unsigned)gx < 128u)
                        acc = fmaf(wc[ky * 3 + kx], xb[gy * 128 + gx], acc);
                }
            }
        }
        v = acc;
    } else {
        v = pos[(c - 112) * 16384 + pix];
    }
    out[idx] = v;   // [b][pix][c]
}

// ---------------- split-fp16 MFMA stride-1 3x3 conv (fp32-parity) ----------------
// Block 256 = 4 waves; patch 16w x 8h, 64 oc per block (grid.z = B*2).
// wm=w&1 -> row half; wn=w>>1 -> oc half (2 n-tiles). ic chunked 2x64 (pad 72).
// 3 MFMAs per product: hi*hi + hi*lo + lo*hi.
template<bool UP2, bool RELU>
__global__ __launch_bounds__(256, 2) void mfma_conv_s1(
    const float* __restrict__ in,
    const _Float16* __restrict__ whi, const _Float16* __restrict__ wlo,
    const float* __restrict__ bias, float* __restrict__ out,
    int H, int W)
{
    __shared__ __align__(16) _Float16 sAh[10 * 18 * 72];
    __shared__ __align__(16) _Float16 sAl[10 * 18 * 72];
    const int tid  = threadIdx.x;
    const int w    = tid >> 6, lane = tid & 63;
    const int wm   = w & 1, wn = w >> 1;
    const int lm   = lane & 15, lq = lane >> 4;
    const int b    = blockIdx.z >> 1;
    const int ocb  = (blockIdx.z & 1) * 64;
    const int x0   = blockIdx.x * 16, y0 = blockIdx.y * 8;
    const int iy0  = y0 - 1, ix0 = x0 - 1;
    const int Hp   = UP2 ? (H >> 1) : H;
    const int Wp   = UP2 ? (W >> 1) : W;
    const float* inb = in + (size_t)b * Hp * Wp * 128;

    f32x4 acc[4][2];
    #pragma unroll
    for (int r = 0; r < 4; ++r)
        #pragma unroll
        for (int nt = 0; nt < 2; ++nt) acc[r][nt] = (f32x4){0.f, 0.f, 0.f, 0.f};

    for (int ics = 0; ics < 128; ics += 64) {
        // stage 18x10 px x 64 ic as hi/lo fp16
        for (int e = tid; e < 180 * 16; e += 256) {
            int px  = e >> 4, icq = e & 15;          // icq: group of 4 ic
            int row = px / 18, col = px - row * 18;
            int gy = iy0 + row, gx = ix0 + col;
            f32x4 v = {0.f, 0.f, 0.f, 0.f};
            if ((unsigned)gy < (unsigned)H && (unsigned)gx < (unsigned)W) {
                int sy = UP2 ? (gy >> 1) : gy;
                int sx = UP2 ? (gx >> 1) : gx;
                v = *(const f32x4*)(inb + ((size_t)sy * Wp + sx) * 128 + ics + icq * 4);
            }
            f16x4 hv, lv;
            #pragma unroll
            for (int j = 0; j < 4; ++j) {
                _Float16 h = (_Float16)v[j];
                hv[j] = h;
                lv[j] = (_Float16)(v[j] - (float)h);
            }
            *(f16x4*)&sAh[px * 72 + icq * 4] = hv;
            *(f16x4*)&sAl[px * 72 + icq * 4] = lv;
        }
        __syncthreads();

        for (int ky = 0; ky < 3; ++ky)
        for (int kx = 0; kx < 3; ++kx) {
            const int tap = ky * 3 + kx;
            const _Float16* wth = whi + (size_t)tap * 16384;
            const _Float16* wtl = wlo + (size_t)tap * 16384;
            #pragma unroll
            for (int kc = 0; kc < 2; ++kc) {
                f16x8 bh[2], bl[2];
                #pragma unroll
                for (int nt = 0; nt < 2; ++nt) {
                    int oc = ocb + wn * 32 + nt * 16 + lm;
                    size_t o = (size_t)oc * 128 + ics + kc * 32 + lq * 8;
                    bh[nt] = *(const f16x8*)(wth + o);
                    bl[nt] = *(const f16x8*)(wtl + o);
                }
                #pragma unroll
                for (int r = 0; r < 4; ++r) {
                    int rin = wm * 4 + r + ky;
                    int cin = lm + kx;
                    int o = (rin * 18 + cin) * 72 + kc * 32 + lq * 8;
                    f16x8 ah = *(const f16x8*)(&sAh[o]);
                    f16x8 al = *(const f16x8*)(&sAl[o]);
                    #pragma unroll
                    for (int nt = 0; nt < 2; ++nt) {
                        acc[r][nt] = __builtin_amdgcn_mfma_f32_16x16x32_f16(ah, bh[nt], acc[r][nt], 0, 0, 0);
                        acc[r][nt] = __builtin_amdgcn_mfma_f32_16x16x32_f16(ah, bl[nt], acc[r][nt], 0, 0, 0);
                        acc[r][nt] = __builtin_amdgcn_mfma_f32_16x16x32_f16(al, bh[nt], acc[r][nt], 0, 0, 0);
                    }
                }
            }
        }
        __syncthreads();
    }

    float bv[2];
    #pragma unroll
    for (int nt = 0; nt < 2; ++nt) bv[nt] = bias[ocb + wn * 32 + nt * 16 + lm];
    float* outb = out + (size_t)b * H * W * 128;
    #pragma unroll
    for (int r = 0; r < 4; ++r) {
        int y = y0 + wm * 4 + r;
        #pragma unroll
        for (int nt = 0; nt < 2; ++nt) {
            int oc = ocb + wn * 32 + nt * 16 + lm;
            #pragma unroll
            for (int reg = 0; reg < 4; ++reg) {
                int xo = x0 + lq * 4 + reg;
                float vv = acc[r][nt][reg] + bv[nt];
                if (RELU) vv = lrelu(vv);
                outb[((size_t)y * W + xo) * 128 + oc] = vv;
            }
        }
    }
}

// ---------------- split-fp16 MFMA stride-2 3x3 conv (fp32-parity) ----------------
// Block 256 = 4 waves; out patch 16w x 4h, all 128 oc (wave -> oc quarter).
// Input tile 9 rows x 33 cols, ic-chunked 4x32 (pad 40).
template<bool RELU>
__global__ __launch_bounds__(256, 2) void mfma_conv_s2(
    const float* __restrict__ in,
    const _Float16* __restrict__ whi, const _Float16* __restrict__ wlo,
    const float* __restrict__ bias, float* __restrict__ out,
    int Hin, int Win)
{
    __shared__ __align__(16) _Float16 sAh[9 * 33 * 40];
    __shared__ __align__(16) _Float16 sAl[9 * 33 * 40];
    const int tid  = threadIdx.x;
    const int w    = tid >> 6, lane = tid & 63;
    const int lm   = lane & 15, lq = lane >> 4;
    const int wn   = w;
    const int b    = blockIdx.z;
    const int Wout = Win >> 1;
    const int x0   = blockIdx.x * 16, y0 = blockIdx.y * 4;
    const int iy0  = blockIdx.y * 8 - 1, ix0 = blockIdx.x * 32 - 1;
    const float* inb = in + (size_t)b * Hin * Win * 128;

    f32x4 acc[4][2];
    #pragma unroll
    for (int r = 0; r < 4; ++r)
        #pragma unroll
        for (int nt = 0; nt < 2; ++nt) acc[r][nt] = (f32x4){0.f, 0.f, 0.f, 0.f};

    for (int kc = 0; kc < 4; ++kc) {
        for (int e = tid; e < 297 * 8; e += 256) {
            int px  = e >> 3, icq = e & 7;           // icq: group of 4 ic
            int row = px / 33, col = px - row * 33;
            int gy = iy0 + row, gx = ix0 + col;
            f32x4 v = {0.f, 0.f, 0.f, 0.f};
            if ((unsigned)gy < (unsigned)Hin && (unsigned)gx < (unsigned)Win)
                v = *(const f32x4*)(inb + ((size_t)gy * Win + gx) * 128 + kc * 32 + icq * 4);
            f16x4 hv, lv;
            #pragma unroll
            for (int j = 0; j < 4; ++j) {
                _Float16 h = (_Float16)v[j];
                hv[j] = h;
                lv[j] = (_Float16)(v[j] - (float)h);
            }
            *(f16x4*)&sAh[px * 40 + icq * 4] = hv;
            *(f16x4*)&sAl[px * 40 + icq * 4] = lv;
        }
        __syncthreads();
        for (int ky = 0; ky < 3; ++ky)
        for (int kx = 0; kx < 3; ++kx) {
            const int tap = ky * 3 + kx;
            const _Float16* wth = whi + (size_t)tap * 16384;
            const _Float16* wtl = wlo + (size_t)tap * 16384;
            f16x8 bh[2], bl[2];
            #pragma unroll
            for (int nt = 0; nt < 2; ++nt) {
                int oc = wn * 32 + nt * 16 + lm;
                size_t o = (size_t)oc * 128 + kc * 32 + lq * 8;
                bh[nt] = *(const f16x8*)(wth + o);
                bl[nt] = *(const f16x8*)(wtl + o);
            }
            #pragma unroll
            for (int r = 0; r < 4; ++r) {
                int rin = 2 * r + ky;
                int cin = 2 * lm + kx;
                int o = (rin * 33 + cin) * 40 + lq * 8;
                f16x8 ah = *(const f16x8*)(&sAh[o]);
                f16x8 al = *(const f16x8*)(&sAl[o]);
                #pragma unroll
                for (int nt = 0; nt < 2; ++nt) {
                    acc[r][nt] = __builtin_amdgcn_mfma_f32_16x16x32_f16(ah, bh[nt], acc[r][nt], 0, 0, 0);
                    acc[r][nt] = __builtin_amdgcn_mfma_f32_16x16x32_f16(ah, bl[nt], acc[r][nt], 0, 0, 0);
                    acc[r][nt] = __builtin_amdgcn_mfma_f32_16x16x32_f16(al, bh[nt], acc[r][nt], 0, 0, 0);
                }
            }
        }
        __syncthreads();
    }

    float bv[2];
    #pragma unroll
    for (int nt = 0; nt < 2; ++nt) bv[nt] = bias[wn * 32 + nt * 16 + lm];
    const int Hout = Hin >> 1;
    float* outb = out + (size_t)b * Hout * Wout * 128;
    #pragma unroll
    for (int r = 0; r < 4; ++r) {
        int y = y0 + r;
        #pragma unroll
        for (int nt = 0; nt < 2; ++nt) {
            int oc = wn * 32 + nt * 16 + lm;
            #pragma unroll
            for (int reg = 0; reg < 4; ++reg) {
                int xo = x0 + lq * 4 + reg;
                float vv = acc[r][nt][reg] + bv[nt];
                if (RELU) vv = lrelu(vv);
                outb[((size_t)y * Wout + xo) * 128 + oc] = vv;
            }
        }
    }
}

// ---------------- per-pixel channel-norm + 1x1 sel conv (fp32 h, wave/pixel) ----------------
__global__ __launch_bounds__(256) void normsel_kernel(
    const float* __restrict__ h, const float* __restrict__ wsel,
    const float* __restrict__ bsel, float* __restrict__ s_lin, int totalPix)
{
    int wid = (blockIdx.x * 256 + threadIdx.x) >> 6;
    if (wid >= totalPix) return;
    int lane = threadIdx.x & 63;
    const float* hb = h + (size_t)wid * 128;
    float v1 = hb[lane], v2 = hb[lane + 64];
    float ss  = v1 * v1 + v2 * v2;
    float dot = wsel[lane] * v1 + wsel[lane + 64] * v2;
    #pragma unroll
    for (int off = 32; off > 0; off >>= 1) {
        ss  += __shfl_down(ss, off);
        dot += __shfl_down(dot, off);
    }
    if (lane == 0) s_lin[wid] = dot / (sqrtf(ss) + 1e-8f) + bsel[0];
}

// ---------------- softmax over 16384, write feat_map ----------------
__global__ __launch_bounds__(256) void softmax_kernel(
    const float* __restrict__ s_lin, float* __restrict__ feat)
{
    int b = blockIdx.x;
    const float* src = s_lin + b * 16384;
    __shared__ float red[256];
    int tid = threadIdx.x;
    float m = -INFINITY;
    for (int i = tid; i < 16384; i += 256) m = fmaxf(m, src[i]);
    red[tid] = m;
    __syncthreads();
    for (int off = 128; off > 0; off >>= 1) {
        if (tid < off) red[tid] = fmaxf(red[tid], red[tid + off]);
        __syncthreads();
    }
    m = red[0];
    __syncthreads();
    float s = 0.f;
    for (int i = tid; i < 16384; i += 256) s += expf(src[i] - m);
    red[tid] = s;
    __syncthreads();
    for (int off = 128; off > 0; off >>= 1) {
        if (tid < off) red[tid] += red[tid + off];
        __syncthreads();
    }
    s = red[0];
    float inv = 1.f / s;
    for (int i = tid; i < 16384; i += 256) feat[b * 16384 + i] = expf(src[i] - m) * inv;
}

// ---------------- top-16: per-thread register top-16 + LDS merge ----------------
__global__ __launch_bounds__(256) void topk_kernel(
    const float* __restrict__ s_lin, int* __restrict__ idxOut)
{
    __shared__ float cv[4096];
    __shared__ int   ci[4096];
    __shared__ float sv[256];
    __shared__ int   si[256];
    __shared__ int   sp[256];
    int b = blockIdx.x;
    const float* src = s_lin + b * 16384;
    int tid = threadIdx.x;
    float tv[16]; int ti[16];
    #pragma unroll
    for (int k = 0; k < 16; ++k) { tv[k] = -INFINITY; ti[k] = 0x7fffffff; }
    for (int i = tid; i < 16384; i += 256) {
        float v = src[i];
        if (v > tv[15]) {
            #pragma unroll
            for (int k = 15; k >= 1; --k) {
                bool sh  = v > tv[k - 1];
                bool ins = (!sh) && (v > tv[k]);
                float nv = sh ? tv[k - 1] : (ins ? v : tv[k]);
                int   ni = sh ? ti[k - 1] : (ins ? i : ti[k]);
                tv[k] = nv; ti[k] = ni;
            }
            bool s0 = v > tv[0];
            tv[0] = s0 ? v : tv[0];
            ti[0] = s0 ? i : ti[0];
        }
    }
    #pragma unroll
    for (int k = 0; k < 16; ++k) { cv[k * 256 + tid] = tv[k]; ci[k * 256 + tid] = ti[k]; }
    __syncthreads();
    for (int k = 0; k < 16; ++k) {
        float bv = -INFINITY; int bi_ = 0x7fffffff; int bp = -1;
        for (int j = tid; j < 4096; j += 256) {
            float v = cv[j]; int id = ci[j];
            if (v > bv || (v == bv && id < bi_)) { bv = v; bi_ = id; bp = j; }
        }
        sv[tid] = bv; si[tid] = bi_; sp[tid] = bp;
        __syncthreads();
        for (int off = 128; off > 0; off >>= 1) {
            if (tid < off) {
                float v2 = sv[tid + off]; int i2 = si[tid + off];
                if (v2 > sv[tid] || (v2 == sv[tid] && i2 < si[tid])) {
                    sv[tid] = v2; si[tid] = i2; sp[tid] = sp[tid + off];
                }
            }
            __syncthreads();
        }
        if (tid == 0) {
            idxOut[b * 16 + k] = si[0] & 16383;   // never emit an OOB index
            cv[sp[0]] = -INFINITY;
        }
        __syncthreads();
    }
}

// ---------------- latents: 1x1 values-conv at 16 selected positions (fp32 h) ----------------
__global__ __launch_bounds__(128) void latents_kernel(
    const float* __restrict__ h, const float* __restrict__ wval,
    const float* __restrict__ bval, const int* __restrict__ tki,
    float* __restrict__ outL, float* __restrict__ zbuf)
{
    int bk = blockIdx.x;          // b*16 + k
    int oc = threadIdx.x;         // 0..127
    int b = bk >> 4;
    int pix = tki[bk] & 16383;
    const float* hb = h + ((size_t)b * 16384 + pix) * 128;
    const float* wr = wval + oc * 128;
    float acc = bval[oc];
    #pragma unroll 8
    for (int ic = 0; ic < 128; ++ic) acc = fmaf(wr[ic], hb[ic], acc);
    outL[bk * 128 + oc] = acc;
    zbuf[bk * 128 + oc] = acc;
}

// ---------------- up-projection z(32,128) @ wup(128,512) + bup ----------------
__global__ __launch_bounds__(256) void upproj_kernel(
    const float* __restrict__ zbuf, const float* __restrict__ wup,
    const float* __restrict__ bup, float* __restrict__ u0, int total)
{
    int idx = blockIdx.x * 256 + threadIdx.x;
    if (idx >= total) return;
    int a = idx >> 9, o = idx & 511;
    const float* z = zbuf + a * 128;
    float acc = bup[o];
    #pragma unroll 8
    for (int k = 0; k < 128; ++k) acc = fmaf(z[k], wup[k * 512 + o], acc);
    u0[idx] = acc;
}

// ---------------- conv1d on 2x-repeated input, k=3 pad=1, + lrelu ----------------
template<int LIN>
__global__ __launch_bounds__(256) void conv1dup_kernel(
    const float* __restrict__ in, const float* __restrict__ w,
    const float* __restrict__ bias, float* __restrict__ out, int total)
{
    constexpr int LOUT = 2 * LIN;
    constexpr int SH = (LIN == 4) ? 3 : (LIN == 8) ? 4 : 5;
    int idx = blockIdx.x * 256 + threadIdx.x;
    if (idx >= total) return;
    int t  = idx & (LOUT - 1);
    int oc = (idx >> SH) & 127;
    int a  = idx >> (SH + 7);
    float acc = bias[oc];
    const float* ib = in + (size_t)a * 128 * LIN;
    const float* wr = w + (size_t)oc * 384;
    int im_ = (t - 1) >> 1, i0 = t >> 1, ip = (t + 1) >> 1;
    bool bm = (t - 1) >= 0, bp = (t + 1) < LOUT;
    #pragma unroll 4
    for (int ic = 0; ic < 128; ++ic) {
        const float* ii = ib + ic * LIN;
        const float* ww = wr + ic * 3;
        if (bm) acc = fmaf(ww[0], ii[im_], acc);
        acc = fmaf(ww[1], ii[i0], acc);
        if (bp) acc = fmaf(ww[2], ii[ip], acc);
    }
    out[idx] = lrelu(acc);
}

// ---------------- fused pointwise heads: amp (sq), fr (sigmoid), mags (sq) ----------------
__global__ __launch_bounds__(256) void heads_kernel(
    const float* __restrict__ u,
    const float* __restrict__ wamp, const float* __restrict__ bamp,
    const float* __restrict__ wfr,  const float* __restrict__ bfr,
    const float* __restrict__ wnz,  const float* __restrict__ bnz,
    float* __restrict__ amp, float* __restrict__ fr, float* __restrict__ mags,
    int total)
{
    int idx = blockIdx.x * 256 + threadIdx.x;
    if (idx >= total) return;
    int t  = idx & 31;
    int oc = (idx >> 5) % 385;
    int a  = idx / (32 * 385);
    const float* ib = u + (size_t)a * 4096 + t;
    const float* wr; float bv;
    if (oc < 128)      { wr = wamp + oc * 128;        bv = bamp[oc]; }
    else if (oc < 256) { wr = wfr + (oc - 128) * 128; bv = bfr[oc - 128]; }
    else               { wr = wnz + (oc - 256) * 128; bv = bnz[oc - 256]; }
    float acc = bv;
    #pragma unroll 8
    for (int ic = 0; ic < 128; ++ic) acc = fmaf(wr[ic], ib[ic * 32], acc);
    if (oc < 128) {
        amp[((size_t)a * 128 + oc) * 32 + t] = acc * acc;
    } else if (oc < 256) {
        float s = 1.f / (1.f + expf(-acc));
        fr[((size_t)a * 128 + (oc - 128)) * 32 + t] = LOWEST_FREQ + s * (1.f - LOWEST_FREQ);
    } else {
        mags[((size_t)a * 129 + (oc - 256)) * 32 + t] = acc * acc;
    }
}

// ---------------- per-(a,c) phase-base prefix in double, reduced mod 1 rev ----------------
__global__ __launch_bounds__(256) void prefix_kernel(
    const float* __restrict__ fr, float* __restrict__ pb, int total)
{
    int i = blockIdx.x * 256 + threadIdx.x;   // a*128 + c
    if (i >= total) return;
    const float* f = fr + i * 32;
    float* p = pb + i * 32;
    double s = 0.0;
    for (int j = 0; j < 32; ++j) {
        double t = 128.0 * s;                 // revolutions accumulated by full blocks
        p[j] = (float)(t - floor(t));
        s += (double)f[j];
    }
}

// ---------------- harmonic synth + scatter-add ----------------
__global__ __launch_bounds__(256) void harm_kernel(
    const float* __restrict__ fr, const float* __restrict__ amp,
    const float* __restrict__ pb, const int* __restrict__ tki,
    float* __restrict__ outp, int total)
{
    int idx = blockIdx.x * 256 + threadIdx.x;
    if (idx >= total) return;
    int a = idx >> 13;
    int i = idx & 8191;
    int j = i >> 8;
    float il1 = (float)((i & 255) + 1);
    int base = a * 4096 + j;                  // (a*128 + c)*32 + j
    float acc = 0.f;
    #pragma unroll 4
    for (int c = 0; c < 128; ++c) {
        int o = base + c * 32;                // wave-uniform -> scalar loads
        float f = fr[o];
        float am = amp[o];
        float p = pb[o];
        float rev = fmaf(il1, 0.5f * f, p);   // phase in revolutions
        acc = fmaf(fast_sin_rev(rev), am, acc);
    }
    int b = a >> 4;
    atomicAdd(outp + (size_t)b * 32768 + (tki[a] & 16383) + i, acc);
}

// ---------------- direct rfft of noise (N=256) ----------------
__global__ __launch_bounds__(256) void spec_kernel(
    const float* __restrict__ noise, float* __restrict__ re,
    float* __restrict__ im, int total)
{
    int idx = blockIdx.x * 256 + threadIdx.x;
    if (idx >= total) return;
    int f  = idx % 129;
    int aw = idx / 129;
    const float* np_ = noise + (size_t)aw * 256;
    float sr = 0.f, si = 0.f;
    for (int n = 0; n < 256; ++n) {
        float rev = (float)(f * n) * (1.0f / 256.0f);
        float c = fast_cos_rev(rev);
        float s = fast_sin_rev(rev);
        float v = np_[n];
        sr = fmaf(v, c, sr);
        si = fmaf(v, -s, si);                 // exp(-i theta)
    }
    re[idx] = sr;
    im[idx] = si;
}

// ---------------- irfft(spec * mags) + scatter-add ----------------
__global__ __launch_bounds__(256) void nz_kernel(
    const float* __restrict__ re, const float* __restrict__ im,
    const float* __restrict__ mags, const int* __restrict__ tki,
    float* __restrict__ outp, int total)
{
    int idx = blockIdx.x * 256 + threadIdx.x;
    if (idx >= total) return;
    int t  = idx & 255;
    int w_ = (idx >> 8) & 31;
    int a  = idx >> 13;
    const float* R = re + ((size_t)a * 32 + w_) * 129;
    const float* I = im + ((size_t)a * 32 + w_) * 129;
    const float* M = mags + (size_t)a * 129 * 32 + w_;   // m[f] = M[f*32]
    float acc = R[0] * M[0];
    #pragma unroll 4
    for (int f = 1; f < 128; ++f) {
        float rev = (float)(f * t) * (1.0f / 256.0f);
        float c = fast_cos_rev(rev);
        float s = fast_sin_rev(rev);
        acc = fmaf(2.f * M[f * 32], fmaf(R[f], c, -I[f] * s), acc);
    }
    float sg = (t & 1) ? -1.f : 1.f;
    acc = fmaf(M[128 * 32] * sg, R[128], acc);
    acc *= (1.f / 256.f);
    int b = a >> 4;
    atomicAdd(outp + (size_t)b * 32768 + (tki[a] & 16383) + (w_ << 8) + t, acc);
}

extern "C" void kernel_launch(void* const* d_in, const int* in_sizes, int n_in,
                              void* d_out, int out_size, void* d_ws, size_t ws_size,
                              hipStream_t stream) {
    (void)n_in; (void)ws_size;
    const float* x    = (const float*)d_in[0];
    const float* pos  = (const float*)d_in[1];
    const float* wi   = (const float*)d_in[2];
    const float* bi   = (const float*)d_in[3];
    const float* wp   = (const float*)d_in[4];
    const float* bp   = (const float*)d_in[5];
    const float* ws1  = (const float*)d_in[6];
    const float* bs1  = (const float*)d_in[7];
    const float* ws2  = (const float*)d_in[8];
    const float* bs2  = (const float*)d_in[9];
    const float* ws3  = (const float*)d_in[10];
    const float* bs3  = (const float*)d_in[11];
    const float* ws4  = (const float*)d_in[12];
    const float* bs4  = (const float*)d_in[13];
    const float* wsb  = (const float*)d_in[14];
    const float* bsb  = (const float*)d_in[15];
    const float* wsel = (const float*)d_in[16];
    const float* bsel = (const float*)d_in[17];
    const float* wval = (const float*)d_in[18];
    const float* bval = (const float*)d_in[19];
    const float* wup  = (const float*)d_in[20];
    const float* bup  = (const float*)d_in[21];
    const float* wu1  = (const float*)d_in[22];
    const float* bu1  = (const float*)d_in[23];
    const float* wu2  = (const float*)d_in[24];
    const float* bu2  = (const float*)d_in[25];
    const float* wu3  = (const float*)d_in[26];
    const float* bu3  = (const float*)d_in[27];
    const float* wamp = (const float*)d_in[28];
    const float* bamp = (const float*)d_in[29];
    const float* wfr  = (const float*)d_in[30];
    const float* bfr  = (const float*)d_in[31];
    const float* wnz  = (const float*)d_in[32];
    const float* bnz  = (const float*)d_in[33];
    const float* noise= (const float*)d_in[34];

    const int B = in_sizes[0] / (128 * 128);   // = 2
    float* outp = (float*)d_out;
    float* outL = outp + (size_t)B * 32768;
    float* feat = outL + (size_t)B * 16 * 128;

    // ---- workspace layout: all regions DISJOINT ----
    // [hb0 fp32][hb1 fp32][whi][wlo][fp32 smalls...]
    const size_t BIGF = (size_t)B * 16384 * 128;       // fp32 feature buffer elements
    float* hb0 = (float*)d_ws;
    float* hb1 = hb0 + BIGF;
    _Float16* whi = (_Float16*)(hb1 + BIGF);
    _Float16* wlo = whi + 6 * 147456;
    float* s_lin = (float*)(wlo + 6 * 147456);
    float* tscr  = s_lin + (size_t)B * 16384;          // spare
    int*   tki   = (int*)(tscr + (size_t)B * 16384);
    float* zbuf  = (float*)(tki + 64);
    float* u0    = zbuf + (size_t)B * 2048;
    float* u1    = u0 + (size_t)B * 65536;
    float* ampb  = u1 + (size_t)B * 65536;
    float* frb   = ampb + (size_t)B * 65536;
    float* pbb   = frb + (size_t)B * 65536;
    float* magsb = pbb + (size_t)B * 65536;
    float* spR   = magsb + (size_t)B * 16 * 129 * 32;
    float* spI   = spR + (size_t)B * 16 * 32 * 129;

    hipMemsetAsync(d_out, 0, (size_t)out_size * sizeof(float), stream);

    repack_kernel<<<(6 * 147456 + 255) / 256, 256, 0, stream>>>(wp, ws1, ws2, ws3, ws4, wsb, whi, wlo);

    // ---- encoder conv chain (channels-last fp32; up2d fused in staging) ----
    {
        int total = B * 128 * 16384;
        conv_in_kernel<<<(total + 255) / 256, 256, 0, stream>>>(x, wi, bi, pos, hb0, total);
    }
    mfma_conv_s1<false, false><<<dim3(8, 16, B * 2), 256, 0, stream>>>(hb0, whi + 0 * 147456, wlo + 0 * 147456, bp,  hb1, 128, 128);
    mfma_conv_s2<true        ><<<dim3(4, 16, B),     256, 0, stream>>>(hb1, whi + 1 * 147456, wlo + 1 * 147456, bs1, hb0, 128, 128);
    mfma_conv_s2<true        ><<<dim3(2, 8,  B),     256, 0, stream>>>(hb0, whi + 2 * 147456, wlo + 2 * 147456, bs2, hb1, 64, 64);
    mfma_conv_s1<true, true  ><<<dim3(4, 8,  B * 2), 256, 0, stream>>>(hb1, whi + 3 * 147456, wlo + 3 * 147456, bs3, hb0, 64, 64);
    mfma_conv_s1<true, true  ><<<dim3(8, 16, B * 2), 256, 0, stream>>>(hb0, whi + 4 * 147456, wlo + 4 * 147456, bs4, hb1, 128, 128);
    mfma_conv_s1<false, false><<<dim3(8, 16, B * 2), 256, 0, stream>>>(hb1, whi + 5 * 147456, wlo + 5 * 147456, bsb, hb0, 128, 128);
    float* h = hb0;   // (B,16384,128) channels-last fp32

    // ---- selection ----
    {
        int totalPix = B * 16384;
        normsel_kernel<<<(totalPix * 64 + 255) / 256, 256, 0, stream>>>(h, wsel, bsel, s_lin, totalPix);
    }
    softmax_kernel<<<B, 256, 0, stream>>>(s_lin, feat);
    topk_kernel<<<B, 256, 0, stream>>>(s_lin, tki);
    latents_kernel<<<B * 16, 128, 0, stream>>>(h, wval, bval, tki, outL, zbuf);

    // ---- decoder ----
    {
        int total = B * 16 * 512;
        upproj_kernel<<<(total + 255) / 256, 256, 0, stream>>>(zbuf, wup, bup, u0, total);
    }
    {
        int total = B * 16 * 128 * 8;
        conv1dup_kernel<4><<<(total + 255) / 256, 256, 0, stream>>>(u0, wu1, bu1, u1, total);
    }
    {
        int total = B * 16 * 128 * 16;
        conv1dup_kernel<8><<<(total + 255) / 256, 256, 0, stream>>>(u1, wu2, bu2, u0, total);
    }
    {
        int total = B * 16 * 128 * 32;
        conv1dup_kernel<16><<<(total + 255) / 256, 256, 0, stream>>>(u0, wu3, bu3, u1, total);
    }
    {
        int total = B * 16 * 385 * 32;
        heads_kernel<<<(total + 255) / 256, 256, 0, stream>>>(u1, wamp, bamp, wfr, bfr, wnz, bnz,
                                                              ampb, frb, magsb, total);
    }
    {
        int total = B * 16 * 128;
        prefix_kernel<<<(total + 255) / 256, 256, 0, stream>>>(frb, pbb, total);
    }
    {
        int total = B * 16 * 8192;
        harm_kernel<<<(total + 255) / 256, 256, 0, stream>>>(frb, ampb, pbb, tki, outp, total);
    }
    {
        int total = B * 16 * 32 * 129;
        spec_kernel<<<(total + 255) / 256, 256, 0, stream>>>(noise, spR, spI, total);
    }
    {
        int total = B * 16 * 32 * 256;
        nz_kernel<<<(total + 255) / 256, 256, 0, stream>>>(spR, spI, magsb, tki, outp, total);
    }
}